// Round 7
// baseline (317.099 us; speedup 1.0000x reference)
//
#include <hip/hip_runtime.h>
#include <math.h>

#define NDET 256
#define NTRK 256
#define NV   512
#define PPTS 512
#define IB   4

typedef short bf16x8 __attribute__((ext_vector_type(8)));
typedef float f32x4  __attribute__((ext_vector_type(4)));

__device__ __forceinline__ float sigf(float x) { return 1.f / (1.f + expf(-x)); }

__device__ __forceinline__ short f2bf(float f) {
    unsigned u = __float_as_uint(f);
    u += 0x7fffu + ((u >> 16) & 1u);          // RNE
    return (short)(u >> 16);
}
__device__ __forceinline__ unsigned pack2bf(float lo, float hi) {
    return (unsigned)(unsigned short)f2bf(lo) | ((unsigned)(unsigned short)f2bf(hi) << 16);
}

// ---------------------------------------------------------------------------
// front_kernel: blocks 0..255 run the fused 2-layer LSTM (one track each);
// blocks 256..767 run PointNet (+det-motion MLP tail). Independent work
// co-executes in one dispatch. LDS both paths ~67.6KB -> 2 blocks/CU.
// ---------------------------------------------------------------------------
__global__ __launch_bounds__(256, 2) void front_kernel(
    const float* __restrict__ det_pts, const float* __restrict__ track_pts,
    const float* __restrict__ w1, const float* __restrict__ b1,
    const float* __restrict__ w2, const float* __restrict__ b2,
    const float* __restrict__ w3, const float* __restrict__ b3,
    const float* __restrict__ det_boxes,
    const float* __restrict__ dw1, const float* __restrict__ db1,
    const float* __restrict__ dw2, const float* __restrict__ db2,
    const float* __restrict__ track_boxes,
    const float* __restrict__ wih0, const float* __restrict__ whh0,
    const float* __restrict__ bih0, const float* __restrict__ bhh0,
    const float* __restrict__ wih1, const float* __restrict__ whh1,
    const float* __restrict__ bih1, const float* __restrict__ bhh1,
    float* __restrict__ hout)
{
    // ---- pointnet shared
    __shared__ __align__(16) short sW2[128][72];
    __shared__ __align__(16) short sW3[64][136];
    __shared__ __align__(16) short sH1[64][72];
    __shared__ __align__(16) short sH2[64][136];
    __shared__ __align__(16) float sX[320];
    __shared__ float sW1f[64][6];
    __shared__ float sB1[64];
    __shared__ float sbox[9];
    __shared__ float sh32[32];
    // ---- lstm shared
    __shared__ float lx[90];
    __shared__ float lg[256];
    __shared__ __align__(16) float lh0[64];
    __shared__ __align__(16) float lh1[64];

    const int t = threadIdx.x;

    if (blockIdx.x < NTRK) {
        // ================= LSTM path =================
        const int m = blockIdx.x;
        const int u = t & 63;

        if (t < 90) lx[t] = track_boxes[m * 90 + t];
        if (t < 64) { lh0[t] = 0.f; lh1[t] = 0.f; }

        float w0[9];
#pragma unroll
        for (int k = 0; k < 9; ++k) w0[k] = wih0[t * 9 + k];
        float4 wr0[16], wi1[16], wr1[16];
        {
            const float4* p0 = (const float4*)(whh0 + t * 64);
            const float4* p1 = (const float4*)(wih1 + t * 64);
            const float4* p2 = (const float4*)(whh1 + t * 64);
#pragma unroll
            for (int k = 0; k < 16; ++k) { wr0[k] = p0[k]; wi1[k] = p1[k]; wr1[k] = p2[k]; }
        }
        const float bias0 = bih0[t] + bhh0[t];
        const float bias1 = bih1[t] + bhh1[t];

        float c0 = 0.f, c1 = 0.f, h1reg = 0.f;
        __syncthreads();

        for (int s = 0; s < 10; ++s) {
            {
                float acc0 = bias0, acc1 = 0.f, acc2 = 0.f, acc3 = 0.f;
#pragma unroll
                for (int k = 0; k < 9; ++k) acc0 = fmaf(w0[k], lx[s * 9 + k], acc0);
                const float4* hv = (const float4*)lh0;
#pragma unroll
                for (int k = 0; k < 16; k += 4) {
                    float4 hA = hv[k], hB = hv[k + 1], hC = hv[k + 2], hD = hv[k + 3];
                    acc0 = fmaf(wr0[k].x, hA.x, acc0); acc0 = fmaf(wr0[k].y, hA.y, acc0);
                    acc0 = fmaf(wr0[k].z, hA.z, acc0); acc0 = fmaf(wr0[k].w, hA.w, acc0);
                    acc1 = fmaf(wr0[k+1].x, hB.x, acc1); acc1 = fmaf(wr0[k+1].y, hB.y, acc1);
                    acc1 = fmaf(wr0[k+1].z, hB.z, acc1); acc1 = fmaf(wr0[k+1].w, hB.w, acc1);
                    acc2 = fmaf(wr0[k+2].x, hC.x, acc2); acc2 = fmaf(wr0[k+2].y, hC.y, acc2);
                    acc2 = fmaf(wr0[k+2].z, hC.z, acc2); acc2 = fmaf(wr0[k+2].w, hC.w, acc2);
                    acc3 = fmaf(wr0[k+3].x, hD.x, acc3); acc3 = fmaf(wr0[k+3].y, hD.y, acc3);
                    acc3 = fmaf(wr0[k+3].z, hD.z, acc3); acc3 = fmaf(wr0[k+3].w, hD.w, acc3);
                }
                lg[t] = (acc0 + acc1) + (acc2 + acc3);
            }
            __syncthreads();
            if (t < 64) {
                const float gi = lg[u], gf = lg[64 + u], gg = lg[128 + u], go = lg[192 + u];
                c0 = sigf(gf) * c0 + sigf(gi) * tanhf(gg);
                lh0[u] = sigf(go) * tanhf(c0);
            }
            __syncthreads();
            {
                float acc0 = bias1, acc1 = 0.f, acc2 = 0.f, acc3 = 0.f;
                const float4* xv = (const float4*)lh0;
                const float4* hv = (const float4*)lh1;
#pragma unroll
                for (int k = 0; k < 16; k += 4) {
                    float4 xA = xv[k], xB = xv[k + 1], xC = xv[k + 2], xD = xv[k + 3];
                    acc0 = fmaf(wi1[k].x, xA.x, acc0); acc0 = fmaf(wi1[k].y, xA.y, acc0);
                    acc0 = fmaf(wi1[k].z, xA.z, acc0); acc0 = fmaf(wi1[k].w, xA.w, acc0);
                    acc1 = fmaf(wi1[k+1].x, xB.x, acc1); acc1 = fmaf(wi1[k+1].y, xB.y, acc1);
                    acc1 = fmaf(wi1[k+1].z, xB.z, acc1); acc1 = fmaf(wi1[k+1].w, xB.w, acc1);
                    acc2 = fmaf(wi1[k+2].x, xC.x, acc2); acc2 = fmaf(wi1[k+2].y, xC.y, acc2);
                    acc2 = fmaf(wi1[k+2].z, xC.z, acc2); acc2 = fmaf(wi1[k+2].w, xC.w, acc2);
                    acc3 = fmaf(wi1[k+3].x, xD.x, acc3); acc3 = fmaf(wi1[k+3].y, xD.y, acc3);
                    acc3 = fmaf(wi1[k+3].z, xD.z, acc3); acc3 = fmaf(wi1[k+3].w, xD.w, acc3);
                }
#pragma unroll
                for (int k = 0; k < 16; k += 4) {
                    float4 hA = hv[k], hB = hv[k + 1], hC = hv[k + 2], hD = hv[k + 3];
                    acc0 = fmaf(wr1[k].x, hA.x, acc0); acc0 = fmaf(wr1[k].y, hA.y, acc0);
                    acc0 = fmaf(wr1[k].z, hA.z, acc0); acc0 = fmaf(wr1[k].w, hA.w, acc0);
                    acc1 = fmaf(wr1[k+1].x, hB.x, acc1); acc1 = fmaf(wr1[k+1].y, hB.y, acc1);
                    acc1 = fmaf(wr1[k+1].z, hB.z, acc1); acc1 = fmaf(wr1[k+1].w, hB.w, acc1);
                    acc2 = fmaf(wr1[k+2].x, hC.x, acc2); acc2 = fmaf(wr1[k+2].y, hC.y, acc2);
                    acc2 = fmaf(wr1[k+2].z, hC.z, acc2); acc2 = fmaf(wr1[k+2].w, hC.w, acc2);
                    acc3 = fmaf(wr1[k+3].x, hD.x, acc3); acc3 = fmaf(wr1[k+3].y, hD.y, acc3);
                    acc3 = fmaf(wr1[k+3].z, hD.z, acc3); acc3 = fmaf(wr1[k+3].w, hD.w, acc3);
                }
                lg[t] = (acc0 + acc1) + (acc2 + acc3);
            }
            __syncthreads();
            if (t < 64) {
                const float gi = lg[u], gf = lg[64 + u], gg = lg[128 + u], go = lg[192 + u];
                c1 = sigf(gf) * c1 + sigf(gi) * tanhf(gg);
                h1reg = sigf(go) * tanhf(c1);
                lh1[u] = h1reg;
            }
            __syncthreads();
        }
        if (t < 64) hout[(size_t)(NDET + m) * 128 + 64 + u] = h1reg;
        return;
    }

    // ================= PointNet path =================
    const int b  = blockIdx.x - NTRK;
    const int w  = t >> 6;
    const int ln = t & 15;
    const int kq = (t >> 4) & 3;
    const float* x = (b < NDET) ? (det_pts + (size_t)b * PPTS * 5)
                                : (track_pts + (size_t)(b - NDET) * PPTS * 5);

    for (int i = t; i < 8192; i += 256) sW2[i >> 6][i & 63] = f2bf(w2[i]);
    for (int i = t; i < 8192; i += 256) sW3[i >> 7][i & 127] = f2bf(w3[i]);
    for (int i = t; i < 320; i += 256) sW1f[i / 5][i % 5] = w1[i];
    if (t < 64) sB1[t] = b1[t];
    __syncthreads();

    bf16x8 bf2[2][2];
#pragma unroll
    for (int nt = 0; nt < 2; ++nt)
#pragma unroll
        for (int Kt = 0; Kt < 2; ++Kt)
            bf2[nt][Kt] = *(const bf16x8*)&sW2[32 * w + 16 * nt + ln][kq * 8 + 32 * Kt];
    bf16x8 bf3[4];
#pragma unroll
    for (int Kt = 0; Kt < 4; ++Kt)
        bf3[Kt] = *(const bf16x8*)&sW3[16 * w + ln][kq * 8 + 32 * Kt];
    float bn[2];
#pragma unroll
    for (int nt = 0; nt < 2; ++nt) bn[nt] = b2[32 * w + 16 * nt + ln];

    float runmax[4] = {-1e30f, -1e30f, -1e30f, -1e30f};

    const int pt = t & 63;
    for (int c = 0; c < PPTS / 64; ++c) {
        for (int i = t; i < 320; i += 256) sX[i] = x[c * 320 + i];
        __syncthreads();
        {
            float xv[5];
#pragma unroll
            for (int k = 0; k < 5; ++k) xv[k] = sX[pt * 5 + k];
#pragma unroll
            for (int jj = 0; jj < 8; ++jj) {
                const int d0 = w * 16 + 2 * jj;
                float a0 = sB1[d0], a1 = sB1[d0 + 1];
#pragma unroll
                for (int k = 0; k < 5; ++k) {
                    a0 = fmaf(xv[k], sW1f[d0][k], a0);
                    a1 = fmaf(xv[k], sW1f[d0 + 1][k], a1);
                }
                *(unsigned*)&sH1[pt][d0] = pack2bf(fmaxf(a0, 0.f), fmaxf(a1, 0.f));
            }
        }
        __syncthreads();
        {
            bf16x8 af[4][2];
#pragma unroll
            for (int Mt = 0; Mt < 4; ++Mt)
#pragma unroll
                for (int Kt = 0; Kt < 2; ++Kt)
                    af[Mt][Kt] = *(const bf16x8*)&sH1[16 * Mt + ln][kq * 8 + 32 * Kt];
#pragma unroll
            for (int Mt = 0; Mt < 4; ++Mt) {
#pragma unroll
                for (int nt = 0; nt < 2; ++nt) {
                    f32x4 cacc = {0.f, 0.f, 0.f, 0.f};
                    cacc = __builtin_amdgcn_mfma_f32_16x16x32_bf16(af[Mt][0], bf2[nt][0], cacc, 0, 0, 0);
                    cacc = __builtin_amdgcn_mfma_f32_16x16x32_bf16(af[Mt][1], bf2[nt][1], cacc, 0, 0, 0);
                    const int col = 32 * w + 16 * nt + ln;
#pragma unroll
                    for (int r = 0; r < 4; ++r)
                        sH2[16 * Mt + kq * 4 + r][col] = f2bf(fmaxf(cacc[r] + bn[nt], 0.f));
                }
            }
        }
        __syncthreads();
        {
#pragma unroll
            for (int Mt = 0; Mt < 4; ++Mt) {
                f32x4 cacc = {0.f, 0.f, 0.f, 0.f};
#pragma unroll
                for (int Kt = 0; Kt < 4; ++Kt) {
                    const bf16x8 a = *(const bf16x8*)&sH2[16 * Mt + ln][kq * 8 + 32 * Kt];
                    cacc = __builtin_amdgcn_mfma_f32_16x16x32_bf16(a, bf3[Kt], cacc, 0, 0, 0);
                }
#pragma unroll
                for (int r = 0; r < 4; ++r) runmax[r] = fmaxf(runmax[r], cacc[r]);
            }
        }
        __syncthreads();
    }

    float rm = fmaxf(fmaxf(runmax[0], runmax[1]), fmaxf(runmax[2], runmax[3]));
    rm = fmaxf(rm, __shfl_xor(rm, 16));
    rm = fmaxf(rm, __shfl_xor(rm, 32));
    if ((t & 63) < 16) {
        const int n = 16 * w + ln;
        hout[b * 128 + n] = rm + b3[n];
    }

    if (b < NDET) {
        if (t < 9) sbox[t] = det_boxes[b * 9 + t];
        __syncthreads();
        if (t < 32) {
            float a = db1[t];
#pragma unroll
            for (int k = 0; k < 9; ++k) a = fmaf(dw1[t * 9 + k], sbox[k], a);
            sh32[t] = fmaxf(a, 0.f);
        }
        __syncthreads();
        if (t < 64) {
            float a = db2[t];
#pragma unroll
            for (int k = 0; k < 32; ++k) a = fmaf(dw2[t * 32 + k], sh32[k], a);
            hout[b * 128 + 64 + t] = a;
        }
    }
}

// ---------------------------------------------------------------------------
// Layer-0 GEMMs, IB=4 rows per block (grid 128): Th = h@wt^T ; Ph = h@wp^T+bp.
// ---------------------------------------------------------------------------
__global__ __launch_bounds__(256) void econv_gemm_kernel(
    const float* __restrict__ hin, const float* __restrict__ wt,
    const float* __restrict__ wp, const float* __restrict__ bp,
    float* __restrict__ Th, float* __restrict__ Ph)
{
    __shared__ __align__(16) float sh[IB][128];
    const int t = threadIdx.x, i0 = blockIdx.x * IB;
    for (int idx = t; idx < IB * 128; idx += 256) sh[idx >> 7][idx & 127] = hin[i0 * 128 + idx];
    __syncthreads();

    const int is = t >> 6, n2 = (t & 63) * 2;
    const float4* hr = (const float4*)sh[is];
    const float4* wA = (const float4*)(wt + (size_t)n2 * 128);
    const float4* wB = (const float4*)(wt + (size_t)(n2 + 1) * 128);
    const float4* pA = (const float4*)(wp + (size_t)n2 * 128);
    const float4* pB = (const float4*)(wp + (size_t)(n2 + 1) * 128);
    float t0 = 0.f, t1 = 0.f, p0 = bp[n2], p1 = bp[n2 + 1];
#pragma unroll 8
    for (int k = 0; k < 32; ++k) {
        const float4 h = hr[k];
        const float4 a = wA[k];
        t0 = fmaf(a.x, h.x, t0); t0 = fmaf(a.y, h.y, t0);
        t0 = fmaf(a.z, h.z, t0); t0 = fmaf(a.w, h.w, t0);
        const float4 b = wB[k];
        t1 = fmaf(b.x, h.x, t1); t1 = fmaf(b.y, h.y, t1);
        t1 = fmaf(b.z, h.z, t1); t1 = fmaf(b.w, h.w, t1);
        const float4 c = pA[k];
        p0 = fmaf(c.x, h.x, p0); p0 = fmaf(c.y, h.y, p0);
        p0 = fmaf(c.z, h.z, p0); p0 = fmaf(c.w, h.w, p0);
        const float4 d = pB[k];
        p1 = fmaf(d.x, h.x, p1); p1 = fmaf(d.y, h.y, p1);
        p1 = fmaf(d.z, h.z, p1); p1 = fmaf(d.w, h.w, p1);
    }
    float2 tv = {t0, t1}, pv = {p0, p1};
    *(float2*)&Th[(size_t)(i0 + is) * 128 + n2] = tv;
    *(float2*)&Ph[(size_t)(i0 + is) * 128 + n2] = pv;
}

// ---------------------------------------------------------------------------
// Fused EdgeConv v2, IB=4 target rows per block (grid 128):
//  - masks for 4 rows as float4 bias (0 / -3e38) in LDS
//  - Th staged in 64-row LDS tiles (read once per block, not per row)
//  - thread (q=dim-quad, jgrp) keeps 4 running-max float4 accumulators
//  - cross-jgrp reduce, combine+relu -> sh rows, then optional next-layer
//    GEMM and optional uproj. Max is associative -> bit-identical.
// ---------------------------------------------------------------------------
__global__ __launch_bounds__(256) void econv_fused_kernel(
    const int* __restrict__ adj, const float* __restrict__ Th,
    const float* __restrict__ Ph, const float* __restrict__ bt,
    const float* __restrict__ wtn, const float* __restrict__ wpn,
    const float* __restrict__ bpn,
    const float* __restrict__ erw1, float* __restrict__ uu,
    float* __restrict__ Thn, float* __restrict__ Phn)
{
    __shared__ __align__(16) float4 sneg[NV];          // bias per j for 4 rows
    __shared__ __align__(16) float sTh[64][132];       // staged Th tile (+pad)
    __shared__ __align__(16) float4 sred[8][IB][32];   // partial maxes
    __shared__ __align__(16) float sh[IB][128];        // output h rows

    const int t = threadIdx.x, i0 = blockIdx.x * IB;
    const int q = t & 31, jgrp = t >> 5;

    for (int idx = t; idx < IB * NV; idx += 256) {
        const int j = idx >> 2, is = idx & 3;
        ((float*)&sneg[j])[is] =
            ((adj[j * NV + i0 + is] != 0) || (j == i0 + is)) ? 0.f : -3e38f;
    }
    __syncthreads();

    float4 mx[IB];
#pragma unroll
    for (int is = 0; is < IB; ++is) { mx[is].x = -3e38f; mx[is].y = -3e38f; mx[is].z = -3e38f; mx[is].w = -3e38f; }

    for (int jb = 0; jb < NV; jb += 64) {
        for (int idx = t; idx < 64 * 32; idx += 256) {
            const int r = idx >> 5, c = idx & 31;
            *(float4*)&sTh[r][4 * c] = *(const float4*)&Th[(size_t)(jb + r) * 128 + 4 * c];
        }
        __syncthreads();
#pragma unroll
        for (int jj = 0; jj < 8; ++jj) {
            const int j = jgrp * 8 + jj;
            const float4 v = *(const float4*)&sTh[j][4 * q];
            const float4 s4 = sneg[jb + j];
            mx[0].x = fmaxf(mx[0].x, v.x + s4.x); mx[0].y = fmaxf(mx[0].y, v.y + s4.x);
            mx[0].z = fmaxf(mx[0].z, v.z + s4.x); mx[0].w = fmaxf(mx[0].w, v.w + s4.x);
            mx[1].x = fmaxf(mx[1].x, v.x + s4.y); mx[1].y = fmaxf(mx[1].y, v.y + s4.y);
            mx[1].z = fmaxf(mx[1].z, v.z + s4.y); mx[1].w = fmaxf(mx[1].w, v.w + s4.y);
            mx[2].x = fmaxf(mx[2].x, v.x + s4.z); mx[2].y = fmaxf(mx[2].y, v.y + s4.z);
            mx[2].z = fmaxf(mx[2].z, v.z + s4.z); mx[2].w = fmaxf(mx[2].w, v.w + s4.z);
            mx[3].x = fmaxf(mx[3].x, v.x + s4.w); mx[3].y = fmaxf(mx[3].y, v.y + s4.w);
            mx[3].z = fmaxf(mx[3].z, v.z + s4.w); mx[3].w = fmaxf(mx[3].w, v.w + s4.w);
        }
        __syncthreads();
    }
#pragma unroll
    for (int is = 0; is < IB; ++is) sred[jgrp][is][q] = mx[is];
    __syncthreads();

    if (t < 128) {
        const int is = t >> 5, qq = t & 31;
        float4 m = sred[0][is][qq];
#pragma unroll
        for (int jg = 1; jg < 8; ++jg) {
            const float4 r = sred[jg][is][qq];
            m.x = fmaxf(m.x, r.x); m.y = fmaxf(m.y, r.y);
            m.z = fmaxf(m.z, r.z); m.w = fmaxf(m.w, r.w);
        }
        const int row = i0 + is;
        const float4 thi = *(const float4*)&Th[(size_t)row * 128 + 4 * qq];
        const float4 phi = *(const float4*)&Ph[(size_t)row * 128 + 4 * qq];
        const float4 btv = *(const float4*)&bt[4 * qq];
        float4 hv;
        hv.x = fmaxf(m.x - thi.x + btv.x + phi.x, 0.f);
        hv.y = fmaxf(m.y - thi.y + btv.y + phi.y, 0.f);
        hv.z = fmaxf(m.z - thi.z + btv.z + phi.z, 0.f);
        hv.w = fmaxf(m.w - thi.w + btv.w + phi.w, 0.f);
        *(float4*)&sh[is][4 * qq] = hv;
    }
    __syncthreads();

    if (wtn) {
        const int is = t >> 6, n2 = (t & 63) * 2;
        const float4* hr = (const float4*)sh[is];
        const float4* wA = (const float4*)(wtn + (size_t)n2 * 128);
        const float4* wB = (const float4*)(wtn + (size_t)(n2 + 1) * 128);
        const float4* pA = (const float4*)(wpn + (size_t)n2 * 128);
        const float4* pB = (const float4*)(wpn + (size_t)(n2 + 1) * 128);
        float t0 = 0.f, t1 = 0.f, p0 = bpn[n2], p1 = bpn[n2 + 1];
#pragma unroll 8
        for (int k = 0; k < 32; ++k) {
            const float4 h = hr[k];
            const float4 a = wA[k];
            t0 = fmaf(a.x, h.x, t0); t0 = fmaf(a.y, h.y, t0);
            t0 = fmaf(a.z, h.z, t0); t0 = fmaf(a.w, h.w, t0);
            const float4 b = wB[k];
            t1 = fmaf(b.x, h.x, t1); t1 = fmaf(b.y, h.y, t1);
            t1 = fmaf(b.z, h.z, t1); t1 = fmaf(b.w, h.w, t1);
            const float4 c = pA[k];
            p0 = fmaf(c.x, h.x, p0); p0 = fmaf(c.y, h.y, p0);
            p0 = fmaf(c.z, h.z, p0); p0 = fmaf(c.w, h.w, p0);
            const float4 d = pB[k];
            p1 = fmaf(d.x, h.x, p1); p1 = fmaf(d.y, h.y, p1);
            p1 = fmaf(d.z, h.z, p1); p1 = fmaf(d.w, h.w, p1);
        }
        float2 tv = {t0, t1}, pv = {p0, p1};
        *(float2*)&Thn[(size_t)(i0 + is) * 128 + n2] = tv;
        *(float2*)&Phn[(size_t)(i0 + is) * 128 + n2] = pv;
    }
    if (erw1 && i0 < NDET) {
        const int is = t >> 6, n = t & 63;
        const float4* hr = (const float4*)sh[is];
        const float4* wr = (const float4*)(erw1 + (size_t)n * 128);
        float a = 0.f;
#pragma unroll 8
        for (int k = 0; k < 32; ++k) {
            const float4 h = hr[k], wv = wr[k];
            a = fmaf(wv.x, h.x, a); a = fmaf(wv.y, h.y, a);
            a = fmaf(wv.z, h.z, a); a = fmaf(wv.w, h.w, a);
        }
        uu[(size_t)(i0 + is) * 64 + n] = a;
    }
}

// ---------------------------------------------------------------------------
// Both affinities in one launch (grid 512): blocks <256 -> aff1 (uu1), else
// aff_final (uu2). aff[i][j] = sigmoid(sum_k w2[k]*relu(u[j]-u[i]+b1) + b2)
// ---------------------------------------------------------------------------
__global__ __launch_bounds__(256) void edge_kernel(
    const float* __restrict__ uu1, const float* __restrict__ uu2,
    const float* __restrict__ b1, const float* __restrict__ w2,
    const float* __restrict__ b2, float* __restrict__ out)
{
    __shared__ float sui[64], sw2[64], sb1[64];
    const int t = threadIdx.x, blk = blockIdx.x;
    const float* u = (blk < NDET) ? uu1 : uu2;
    float* o = (blk < NDET) ? out : out + NDET * NTRK;
    const int i = blk & (NDET - 1);
    if (t < 64) { sui[t] = u[i * 64 + t]; sw2[t] = w2[t]; sb1[t] = b1[t]; }
    __syncthreads();
    const float4* ur = (const float4*)(u + t * 64);
    float a = b2[0];
#pragma unroll
    for (int k = 0; k < 16; ++k) {
        const float4 uv = ur[k];
        const int k4 = k * 4;
        a = fmaf(sw2[k4 + 0], fmaxf(uv.x - sui[k4 + 0] + sb1[k4 + 0], 0.f), a);
        a = fmaf(sw2[k4 + 1], fmaxf(uv.y - sui[k4 + 1] + sb1[k4 + 1], 0.f), a);
        a = fmaf(sw2[k4 + 2], fmaxf(uv.z - sui[k4 + 2] + sb1[k4 + 2], 0.f), a);
        a = fmaf(sw2[k4 + 3], fmaxf(uv.w - sui[k4 + 3] + sb1[k4 + 3], 0.f), a);
    }
    o[i * 256 + t] = 1.f / (1.f + expf(-a));
}

// ---------------------------------------------------------------------------
extern "C" void kernel_launch(void* const* d_in, const int* in_sizes, int n_in,
                              void* d_out, int out_size, void* d_ws, size_t ws_size,
                              hipStream_t stream)
{
    const float* det_pts     = (const float*)d_in[0];
    const float* det_boxes   = (const float*)d_in[1];
    const float* track_pts   = (const float*)d_in[2];
    const float* track_boxes = (const float*)d_in[3];
    const int*   adj         = (const int*)d_in[4];
    const float* pn_w1 = (const float*)d_in[5],  *pn_b1 = (const float*)d_in[6];
    const float* pn_w2 = (const float*)d_in[7],  *pn_b2 = (const float*)d_in[8];
    const float* pn_w3 = (const float*)d_in[9],  *pn_b3 = (const float*)d_in[10];
    const float* dm_w1 = (const float*)d_in[11], *dm_b1 = (const float*)d_in[12];
    const float* dm_w2 = (const float*)d_in[13], *dm_b2 = (const float*)d_in[14];
    const float* l0_wih = (const float*)d_in[15], *l0_whh = (const float*)d_in[16];
    const float* l0_bih = (const float*)d_in[17], *l0_bhh = (const float*)d_in[18];
    const float* l1_wih = (const float*)d_in[19], *l1_whh = (const float*)d_in[20];
    const float* l1_bih = (const float*)d_in[21], *l1_bhh = (const float*)d_in[22];
    const float* gc_wt = (const float*)d_in[23], *gc_bt = (const float*)d_in[24];
    const float* gc_wp = (const float*)d_in[25], *gc_bp = (const float*)d_in[26];
    const float* er_w1 = (const float*)d_in[27], *er_b1 = (const float*)d_in[28];
    const float* er_w2 = (const float*)d_in[29], *er_b2 = (const float*)d_in[30];
    float* out = (float*)d_out;

    float* hA  = (float*)d_ws;           // [512][128]
    float* Th  = hA  + NV * 128;         // [512][128]
    float* Ph  = Th  + NV * 128;         // [512][128]
    float* Th2 = Ph  + NV * 128;         // [512][128]
    float* Ph2 = Th2 + NV * 128;         // [512][128]
    float* uu1 = Ph2 + NV * 128;         // [256][64]
    float* uu2 = uu1 + NDET * 64;        // [256][64]

    front_kernel<<<NTRK + NV, 256, 0, stream>>>(det_pts, track_pts,
        pn_w1, pn_b1, pn_w2, pn_b2, pn_w3, pn_b3,
        det_boxes, dm_w1, dm_b1, dm_w2, dm_b2,
        track_boxes, l0_wih, l0_whh, l0_bih, l0_bhh,
        l1_wih, l1_whh, l1_bih, l1_bhh, hA);

    econv_gemm_kernel<<<NV / IB, 256, 0, stream>>>(hA, gc_wt, gc_wp, gc_bp, Th, Ph);

    const size_t WSZ = 128 * 128;
    econv_fused_kernel<<<NV / IB, 256, 0, stream>>>(adj, Th, Ph, gc_bt,
        gc_wt + WSZ, gc_wp + WSZ, gc_bp + 128, er_w1, uu1, Th2, Ph2);
    econv_fused_kernel<<<NV / IB, 256, 0, stream>>>(adj, Th2, Ph2, gc_bt + 128,
        gc_wt + 2 * WSZ, gc_wp + 2 * WSZ, gc_bp + 256, nullptr, nullptr, Th, Ph);
    econv_fused_kernel<<<NV / IB, 256, 0, stream>>>(adj, Th, Ph, gc_bt + 256,
        gc_wt + 3 * WSZ, gc_wp + 3 * WSZ, gc_bp + 384, nullptr, nullptr, Th2, Ph2);
    econv_fused_kernel<<<NDET / IB, 256, 0, stream>>>(adj, Th2, Ph2, gc_bt + 384,
        nullptr, nullptr, nullptr, er_w1, uu2, nullptr, nullptr);

    edge_kernel<<<NV, 256, 0, stream>>>(uu1, uu2, er_b1, er_w2, er_b2, out);
}

// Round 8
// 263.572 us; speedup vs baseline: 1.2031x; 1.2031x over previous
//
#include <hip/hip_runtime.h>
#include <math.h>

#define NDET 256
#define NTRK 256
#define NV   512
#define PPTS 512

typedef short bf16x8 __attribute__((ext_vector_type(8)));
typedef float f32x4  __attribute__((ext_vector_type(4)));

__device__ __forceinline__ float sigf(float x) { return 1.f / (1.f + expf(-x)); }

__device__ __forceinline__ short f2bf(float f) {
    unsigned u = __float_as_uint(f);
    u += 0x7fffu + ((u >> 16) & 1u);          // RNE
    return (short)(u >> 16);
}
__device__ __forceinline__ unsigned pack2bf(float lo, float hi) {
    return (unsigned)(unsigned short)f2bf(lo) | ((unsigned)(unsigned short)f2bf(hi) << 16);
}

// ---------------------------------------------------------------------------
// front_kernel: blocks 0..255 = fused 2-layer LSTM (one track each);
// blocks 256..767 = PointNet (+det-motion tail). launch_bounds(256,1):
// VGPR cap 512 so the LSTM weight set (~200 regs) does NOT spill — round-6's
// (256,2) made the compiler pick 128 VGPRs and spill (the regression).
// LDS ~66.5KB -> 2 blocks/CU; VGPR 256 -> 2 waves/SIMD. Consistent.
// ---------------------------------------------------------------------------
__global__ __launch_bounds__(256, 1) void front_kernel(
    const float* __restrict__ det_pts, const float* __restrict__ track_pts,
    const float* __restrict__ w1, const float* __restrict__ b1,
    const float* __restrict__ w2, const float* __restrict__ b2,
    const float* __restrict__ w3, const float* __restrict__ b3,
    const float* __restrict__ det_boxes,
    const float* __restrict__ dw1, const float* __restrict__ db1,
    const float* __restrict__ dw2, const float* __restrict__ db2,
    const float* __restrict__ track_boxes,
    const float* __restrict__ wih0, const float* __restrict__ whh0,
    const float* __restrict__ bih0, const float* __restrict__ bhh0,
    const float* __restrict__ wih1, const float* __restrict__ whh1,
    const float* __restrict__ bih1, const float* __restrict__ bhh1,
    float* __restrict__ hout)
{
    // ---- pointnet shared
    __shared__ __align__(16) short sW2[128][72];
    __shared__ __align__(16) short sW3[64][136];
    __shared__ __align__(16) short sH1[64][72];
    __shared__ __align__(16) short sH2[64][136];
    __shared__ __align__(16) float sX[320];
    __shared__ float sW1f[64][6];
    __shared__ float sB1[64];
    __shared__ float sbox[9];
    __shared__ float sh32[32];
    // ---- lstm shared
    __shared__ float lx[90];
    __shared__ float lg[256];
    __shared__ __align__(16) float lh0[64];
    __shared__ __align__(16) float lh1[64];

    const int t = threadIdx.x;

    if (blockIdx.x < NTRK) {
        // ================= LSTM path =================
        const int m = blockIdx.x;
        const int u = t & 63;

        if (t < 90) lx[t] = track_boxes[m * 90 + t];
        if (t < 64) { lh0[t] = 0.f; lh1[t] = 0.f; }

        float w0[9];
#pragma unroll
        for (int k = 0; k < 9; ++k) w0[k] = wih0[t * 9 + k];
        float4 wr0[16], wi1[16], wr1[16];
        {
            const float4* p0 = (const float4*)(whh0 + t * 64);
            const float4* p1 = (const float4*)(wih1 + t * 64);
            const float4* p2 = (const float4*)(whh1 + t * 64);
#pragma unroll
            for (int k = 0; k < 16; ++k) { wr0[k] = p0[k]; wi1[k] = p1[k]; wr1[k] = p2[k]; }
        }
        const float bias0 = bih0[t] + bhh0[t];
        const float bias1 = bih1[t] + bhh1[t];

        float c0 = 0.f, c1 = 0.f, h1reg = 0.f;
        __syncthreads();

        for (int s = 0; s < 10; ++s) {
            {
                float acc0 = bias0, acc1 = 0.f, acc2 = 0.f, acc3 = 0.f;
#pragma unroll
                for (int k = 0; k < 9; ++k) acc0 = fmaf(w0[k], lx[s * 9 + k], acc0);
                const float4* hv = (const float4*)lh0;
#pragma unroll
                for (int k = 0; k < 16; k += 4) {
                    float4 hA = hv[k], hB = hv[k + 1], hC = hv[k + 2], hD = hv[k + 3];
                    acc0 = fmaf(wr0[k].x, hA.x, acc0); acc0 = fmaf(wr0[k].y, hA.y, acc0);
                    acc0 = fmaf(wr0[k].z, hA.z, acc0); acc0 = fmaf(wr0[k].w, hA.w, acc0);
                    acc1 = fmaf(wr0[k+1].x, hB.x, acc1); acc1 = fmaf(wr0[k+1].y, hB.y, acc1);
                    acc1 = fmaf(wr0[k+1].z, hB.z, acc1); acc1 = fmaf(wr0[k+1].w, hB.w, acc1);
                    acc2 = fmaf(wr0[k+2].x, hC.x, acc2); acc2 = fmaf(wr0[k+2].y, hC.y, acc2);
                    acc2 = fmaf(wr0[k+2].z, hC.z, acc2); acc2 = fmaf(wr0[k+2].w, hC.w, acc2);
                    acc3 = fmaf(wr0[k+3].x, hD.x, acc3); acc3 = fmaf(wr0[k+3].y, hD.y, acc3);
                    acc3 = fmaf(wr0[k+3].z, hD.z, acc3); acc3 = fmaf(wr0[k+3].w, hD.w, acc3);
                }
                lg[t] = (acc0 + acc1) + (acc2 + acc3);
            }
            __syncthreads();
            if (t < 64) {
                const float gi = lg[u], gf = lg[64 + u], gg = lg[128 + u], go = lg[192 + u];
                c0 = sigf(gf) * c0 + sigf(gi) * tanhf(gg);
                lh0[u] = sigf(go) * tanhf(c0);
            }
            __syncthreads();
            {
                float acc0 = bias1, acc1 = 0.f, acc2 = 0.f, acc3 = 0.f;
                const float4* xv = (const float4*)lh0;
                const float4* hv = (const float4*)lh1;
#pragma unroll
                for (int k = 0; k < 16; k += 4) {
                    float4 xA = xv[k], xB = xv[k + 1], xC = xv[k + 2], xD = xv[k + 3];
                    acc0 = fmaf(wi1[k].x, xA.x, acc0); acc0 = fmaf(wi1[k].y, xA.y, acc0);
                    acc0 = fmaf(wi1[k].z, xA.z, acc0); acc0 = fmaf(wi1[k].w, xA.w, acc0);
                    acc1 = fmaf(wi1[k+1].x, xB.x, acc1); acc1 = fmaf(wi1[k+1].y, xB.y, acc1);
                    acc1 = fmaf(wi1[k+1].z, xB.z, acc1); acc1 = fmaf(wi1[k+1].w, xB.w, acc1);
                    acc2 = fmaf(wi1[k+2].x, xC.x, acc2); acc2 = fmaf(wi1[k+2].y, xC.y, acc2);
                    acc2 = fmaf(wi1[k+2].z, xC.z, acc2); acc2 = fmaf(wi1[k+2].w, xC.w, acc2);
                    acc3 = fmaf(wi1[k+3].x, xD.x, acc3); acc3 = fmaf(wi1[k+3].y, xD.y, acc3);
                    acc3 = fmaf(wi1[k+3].z, xD.z, acc3); acc3 = fmaf(wi1[k+3].w, xD.w, acc3);
                }
#pragma unroll
                for (int k = 0; k < 16; k += 4) {
                    float4 hA = hv[k], hB = hv[k + 1], hC = hv[k + 2], hD = hv[k + 3];
                    acc0 = fmaf(wr1[k].x, hA.x, acc0); acc0 = fmaf(wr1[k].y, hA.y, acc0);
                    acc0 = fmaf(wr1[k].z, hA.z, acc0); acc0 = fmaf(wr1[k].w, hA.w, acc0);
                    acc1 = fmaf(wr1[k+1].x, hB.x, acc1); acc1 = fmaf(wr1[k+1].y, hB.y, acc1);
                    acc1 = fmaf(wr1[k+1].z, hB.z, acc1); acc1 = fmaf(wr1[k+1].w, hB.w, acc1);
                    acc2 = fmaf(wr1[k+2].x, hC.x, acc2); acc2 = fmaf(wr1[k+2].y, hC.y, acc2);
                    acc2 = fmaf(wr1[k+2].z, hC.z, acc2); acc2 = fmaf(wr1[k+2].w, hC.w, acc2);
                    acc3 = fmaf(wr1[k+3].x, hD.x, acc3); acc3 = fmaf(wr1[k+3].y, hD.y, acc3);
                    acc3 = fmaf(wr1[k+3].z, hD.z, acc3); acc3 = fmaf(wr1[k+3].w, hD.w, acc3);
                }
                lg[t] = (acc0 + acc1) + (acc2 + acc3);
            }
            __syncthreads();
            if (t < 64) {
                const float gi = lg[u], gf = lg[64 + u], gg = lg[128 + u], go = lg[192 + u];
                c1 = sigf(gf) * c1 + sigf(gi) * tanhf(gg);
                h1reg = sigf(go) * tanhf(c1);
                lh1[u] = h1reg;
            }
            __syncthreads();
        }
        if (t < 64) hout[(size_t)(NDET + m) * 128 + 64 + u] = h1reg;
        return;
    }

    // ================= PointNet path =================
    const int b  = blockIdx.x - NTRK;
    const int w  = t >> 6;
    const int ln = t & 15;
    const int kq = (t >> 4) & 3;
    const float* x = (b < NDET) ? (det_pts + (size_t)b * PPTS * 5)
                                : (track_pts + (size_t)(b - NDET) * PPTS * 5);

    for (int i = t; i < 8192; i += 256) sW2[i >> 6][i & 63] = f2bf(w2[i]);
    for (int i = t; i < 8192; i += 256) sW3[i >> 7][i & 127] = f2bf(w3[i]);
    for (int i = t; i < 320; i += 256) sW1f[i / 5][i % 5] = w1[i];
    if (t < 64) sB1[t] = b1[t];
    __syncthreads();

    bf16x8 bf2[2][2];
#pragma unroll
    for (int nt = 0; nt < 2; ++nt)
#pragma unroll
        for (int Kt = 0; Kt < 2; ++Kt)
            bf2[nt][Kt] = *(const bf16x8*)&sW2[32 * w + 16 * nt + ln][kq * 8 + 32 * Kt];
    bf16x8 bf3[4];
#pragma unroll
    for (int Kt = 0; Kt < 4; ++Kt)
        bf3[Kt] = *(const bf16x8*)&sW3[16 * w + ln][kq * 8 + 32 * Kt];
    float bn[2];
#pragma unroll
    for (int nt = 0; nt < 2; ++nt) bn[nt] = b2[32 * w + 16 * nt + ln];

    float runmax[4] = {-1e30f, -1e30f, -1e30f, -1e30f};

    const int pt = t & 63;
    for (int c = 0; c < PPTS / 64; ++c) {
        for (int i = t; i < 320; i += 256) sX[i] = x[c * 320 + i];
        __syncthreads();
        {
            float xv[5];
#pragma unroll
            for (int k = 0; k < 5; ++k) xv[k] = sX[pt * 5 + k];
#pragma unroll
            for (int jj = 0; jj < 8; ++jj) {
                const int d0 = w * 16 + 2 * jj;
                float a0 = sB1[d0], a1 = sB1[d0 + 1];
#pragma unroll
                for (int k = 0; k < 5; ++k) {
                    a0 = fmaf(xv[k], sW1f[d0][k], a0);
                    a1 = fmaf(xv[k], sW1f[d0 + 1][k], a1);
                }
                *(unsigned*)&sH1[pt][d0] = pack2bf(fmaxf(a0, 0.f), fmaxf(a1, 0.f));
            }
        }
        __syncthreads();
        {
            bf16x8 af[4][2];
#pragma unroll
            for (int Mt = 0; Mt < 4; ++Mt)
#pragma unroll
                for (int Kt = 0; Kt < 2; ++Kt)
                    af[Mt][Kt] = *(const bf16x8*)&sH1[16 * Mt + ln][kq * 8 + 32 * Kt];
#pragma unroll
            for (int Mt = 0; Mt < 4; ++Mt) {
#pragma unroll
                for (int nt = 0; nt < 2; ++nt) {
                    f32x4 cacc = {0.f, 0.f, 0.f, 0.f};
                    cacc = __builtin_amdgcn_mfma_f32_16x16x32_bf16(af[Mt][0], bf2[nt][0], cacc, 0, 0, 0);
                    cacc = __builtin_amdgcn_mfma_f32_16x16x32_bf16(af[Mt][1], bf2[nt][1], cacc, 0, 0, 0);
                    const int col = 32 * w + 16 * nt + ln;
#pragma unroll
                    for (int r = 0; r < 4; ++r)
                        sH2[16 * Mt + kq * 4 + r][col] = f2bf(fmaxf(cacc[r] + bn[nt], 0.f));
                }
            }
        }
        __syncthreads();
        {
#pragma unroll
            for (int Mt = 0; Mt < 4; ++Mt) {
                f32x4 cacc = {0.f, 0.f, 0.f, 0.f};
#pragma unroll
                for (int Kt = 0; Kt < 4; ++Kt) {
                    const bf16x8 a = *(const bf16x8*)&sH2[16 * Mt + ln][kq * 8 + 32 * Kt];
                    cacc = __builtin_amdgcn_mfma_f32_16x16x32_bf16(a, bf3[Kt], cacc, 0, 0, 0);
                }
#pragma unroll
                for (int r = 0; r < 4; ++r) runmax[r] = fmaxf(runmax[r], cacc[r]);
            }
        }
        __syncthreads();
    }

    float rm = fmaxf(fmaxf(runmax[0], runmax[1]), fmaxf(runmax[2], runmax[3]));
    rm = fmaxf(rm, __shfl_xor(rm, 16));
    rm = fmaxf(rm, __shfl_xor(rm, 32));
    if ((t & 63) < 16) {
        const int n = 16 * w + ln;
        hout[b * 128 + n] = rm + b3[n];
    }

    if (b < NDET) {
        if (t < 9) sbox[t] = det_boxes[b * 9 + t];
        __syncthreads();
        if (t < 32) {
            float a = db1[t];
#pragma unroll
            for (int k = 0; k < 9; ++k) a = fmaf(dw1[t * 9 + k], sbox[k], a);
            sh32[t] = fmaxf(a, 0.f);
        }
        __syncthreads();
        if (t < 64) {
            float a = db2[t];
#pragma unroll
            for (int k = 0; k < 32; ++k) a = fmaf(dw2[t * 32 + k], sh32[k], a);
            hout[b * 128 + 64 + t] = a;
        }
    }
}

// ---------------------------------------------------------------------------
// EdgeConv layer-0 GEMMs (round-5 version): one block per vertex.
// ---------------------------------------------------------------------------
__global__ __launch_bounds__(128) void econv_gemm_kernel(
    const float* __restrict__ hin, const float* __restrict__ wt,
    const float* __restrict__ wp, const float* __restrict__ bp,
    float* __restrict__ Th, float* __restrict__ Ph)
{
    __shared__ __align__(16) float srow[128];
    const int t = threadIdx.x, v = blockIdx.x;
    srow[t] = hin[v * 128 + t];
    __syncthreads();
    const float4* hr = (const float4*)srow;
    const float4* wtr = (const float4*)(wt + t * 128);
    const float4* wpr = (const float4*)(wp + t * 128);
    float aT = 0.f, aP = bp[t];
#pragma unroll 8
    for (int k = 0; k < 32; ++k) {
        const float4 h = hr[k];
        const float4 a = wtr[k];
        aT = fmaf(a.x, h.x, aT); aT = fmaf(a.y, h.y, aT);
        aT = fmaf(a.z, h.z, aT); aT = fmaf(a.w, h.w, aT);
        const float4 b = wpr[k];
        aP = fmaf(b.x, h.x, aP); aP = fmaf(b.y, h.y, aP);
        aP = fmaf(b.z, h.z, aP); aP = fmaf(b.w, h.w, aP);
    }
    Th[v * 128 + t] = aT;
    Ph[v * 128 + t] = aP;
}

// ---------------------------------------------------------------------------
// Fused EdgeConv (round-5 version): masked neighbor-max + combine + relu
// (h_i stays in LDS), then optional next-layer GEMM and optional uproj.
// ---------------------------------------------------------------------------
__global__ __launch_bounds__(128) void econv_fused_kernel(
    const int* __restrict__ adj, const float* __restrict__ Th,
    const float* __restrict__ Ph, const float* __restrict__ bt,
    const float* __restrict__ wtn, const float* __restrict__ wpn,
    const float* __restrict__ bpn,
    const float* __restrict__ erw1, float* __restrict__ uu,
    float* __restrict__ Thn, float* __restrict__ Phn)
{
    __shared__ float sneg[NV];                       // 0 / -3e38 mask bias
    __shared__ __align__(16) float4 sred[4][32];     // per-group partial max
    __shared__ __align__(16) float sh[128];          // h_i row

    const int t = threadIdx.x, i = blockIdx.x;
    const int l32 = t & 31, grp = t >> 5;

    for (int j = t; j < NV; j += 128)
        sneg[j] = ((adj[j * NV + i] != 0) || (j == i)) ? 0.f : -3e38f;

    const float thi = Th[i * 128 + t];
    const float phi = Ph[i * 128 + t];
    const float btv = bt[t];
    __syncthreads();

    float4 mx = {-3e38f, -3e38f, -3e38f, -3e38f};
    const float* __restrict__ thp = Th + 4 * l32;
#pragma unroll 4
    for (int jb = 0; jb < NV; jb += 16) {
        float4 v[4];
#pragma unroll
        for (int jj = 0; jj < 4; ++jj)
            v[jj] = *(const float4*)&thp[(size_t)(jb + 4 * jj + grp) * 128];
#pragma unroll
        for (int jj = 0; jj < 4; ++jj) {
            const float s = sneg[jb + 4 * jj + grp];
            mx.x = fmaxf(mx.x, v[jj].x + s);
            mx.y = fmaxf(mx.y, v[jj].y + s);
            mx.z = fmaxf(mx.z, v[jj].z + s);
            mx.w = fmaxf(mx.w, v[jj].w + s);
        }
    }
    sred[grp][l32] = mx;
    __syncthreads();

    const float* rf = (const float*)sred;
    const float m = fmaxf(fmaxf(rf[t], rf[128 + t]), fmaxf(rf[256 + t], rf[384 + t]));
    sh[t] = fmaxf(m - thi + btv + phi, 0.f);
    __syncthreads();

    const float4* hr = (const float4*)sh;
    if (wtn) {
        const float4* wtr = (const float4*)(wtn + t * 128);
        const float4* wpr = (const float4*)(wpn + t * 128);
        float aT = 0.f, aP = bpn[t];
#pragma unroll 8
        for (int k = 0; k < 32; ++k) {
            const float4 h = hr[k];
            const float4 a = wtr[k];
            aT = fmaf(a.x, h.x, aT); aT = fmaf(a.y, h.y, aT);
            aT = fmaf(a.z, h.z, aT); aT = fmaf(a.w, h.w, aT);
            const float4 b = wpr[k];
            aP = fmaf(b.x, h.x, aP); aP = fmaf(b.y, h.y, aP);
            aP = fmaf(b.z, h.z, aP); aP = fmaf(b.w, h.w, aP);
        }
        Thn[i * 128 + t] = aT;
        Phn[i * 128 + t] = aP;
    }
    if (erw1 && i < NDET && t < 64) {
        const float4* wr = (const float4*)(erw1 + t * 128);
        float a = 0.f;
#pragma unroll 8
        for (int k = 0; k < 32; ++k) {
            const float4 h = hr[k], wv = wr[k];
            a = fmaf(wv.x, h.x, a); a = fmaf(wv.y, h.y, a);
            a = fmaf(wv.z, h.z, a); a = fmaf(wv.w, h.w, a);
        }
        uu[i * 64 + t] = a;
    }
}

// ---------------------------------------------------------------------------
// Both affinities in one launch (grid 512): blocks <256 -> aff1, else final.
// ---------------------------------------------------------------------------
__global__ __launch_bounds__(256) void edge_kernel(
    const float* __restrict__ uu1, const float* __restrict__ uu2,
    const float* __restrict__ b1, const float* __restrict__ w2,
    const float* __restrict__ b2, float* __restrict__ out)
{
    __shared__ float sui[64], sw2[64], sb1[64];
    const int t = threadIdx.x, blk = blockIdx.x;
    const float* u = (blk < NDET) ? uu1 : uu2;
    float* o = (blk < NDET) ? out : out + NDET * NTRK;
    const int i = blk & (NDET - 1);
    if (t < 64) { sui[t] = u[i * 64 + t]; sw2[t] = w2[t]; sb1[t] = b1[t]; }
    __syncthreads();
    const float4* ur = (const float4*)(u + t * 64);
    float a = b2[0];
#pragma unroll
    for (int k = 0; k < 16; ++k) {
        const float4 uv = ur[k];
        const int k4 = k * 4;
        a = fmaf(sw2[k4 + 0], fmaxf(uv.x - sui[k4 + 0] + sb1[k4 + 0], 0.f), a);
        a = fmaf(sw2[k4 + 1], fmaxf(uv.y - sui[k4 + 1] + sb1[k4 + 1], 0.f), a);
        a = fmaf(sw2[k4 + 2], fmaxf(uv.z - sui[k4 + 2] + sb1[k4 + 2], 0.f), a);
        a = fmaf(sw2[k4 + 3], fmaxf(uv.w - sui[k4 + 3] + sb1[k4 + 3], 0.f), a);
    }
    o[i * 256 + t] = 1.f / (1.f + expf(-a));
}

// ---------------------------------------------------------------------------
extern "C" void kernel_launch(void* const* d_in, const int* in_sizes, int n_in,
                              void* d_out, int out_size, void* d_ws, size_t ws_size,
                              hipStream_t stream)
{
    const float* det_pts     = (const float*)d_in[0];
    const float* det_boxes   = (const float*)d_in[1];
    const float* track_pts   = (const float*)d_in[2];
    const float* track_boxes = (const float*)d_in[3];
    const int*   adj         = (const int*)d_in[4];
    const float* pn_w1 = (const float*)d_in[5],  *pn_b1 = (const float*)d_in[6];
    const float* pn_w2 = (const float*)d_in[7],  *pn_b2 = (const float*)d_in[8];
    const float* pn_w3 = (const float*)d_in[9],  *pn_b3 = (const float*)d_in[10];
    const float* dm_w1 = (const float*)d_in[11], *dm_b1 = (const float*)d_in[12];
    const float* dm_w2 = (const float*)d_in[13], *dm_b2 = (const float*)d_in[14];
    const float* l0_wih = (const float*)d_in[15], *l0_whh = (const float*)d_in[16];
    const float* l0_bih = (const float*)d_in[17], *l0_bhh = (const float*)d_in[18];
    const float* l1_wih = (const float*)d_in[19], *l1_whh = (const float*)d_in[20];
    const float* l1_bih = (const float*)d_in[21], *l1_bhh = (const float*)d_in[22];
    const float* gc_wt = (const float*)d_in[23], *gc_bt = (const float*)d_in[24];
    const float* gc_wp = (const float*)d_in[25], *gc_bp = (const float*)d_in[26];
    const float* er_w1 = (const float*)d_in[27], *er_b1 = (const float*)d_in[28];
    const float* er_w2 = (const float*)d_in[29], *er_b2 = (const float*)d_in[30];
    float* out = (float*)d_out;

    float* hA  = (float*)d_ws;           // [512][128]
    float* Th  = hA  + NV * 128;         // [512][128]
    float* Ph  = Th  + NV * 128;         // [512][128]
    float* Th2 = Ph  + NV * 128;         // [512][128]
    float* Ph2 = Th2 + NV * 128;         // [512][128]
    float* uu1 = Ph2 + NV * 128;         // [256][64]
    float* uu2 = uu1 + NDET * 64;        // [256][64]

    front_kernel<<<NTRK + NV, 256, 0, stream>>>(det_pts, track_pts,
        pn_w1, pn_b1, pn_w2, pn_b2, pn_w3, pn_b3,
        det_boxes, dm_w1, dm_b1, dm_w2, dm_b2,
        track_boxes, l0_wih, l0_whh, l0_bih, l0_bhh,
        l1_wih, l1_whh, l1_bih, l1_bhh, hA);

    econv_gemm_kernel<<<NV, 128, 0, stream>>>(hA, gc_wt, gc_wp, gc_bp, Th, Ph);

    const size_t WSZ = 128 * 128;
    econv_fused_kernel<<<NV, 128, 0, stream>>>(adj, Th, Ph, gc_bt,
        gc_wt + WSZ, gc_wp + WSZ, gc_bp + 128, er_w1, uu1, Th2, Ph2);
    econv_fused_kernel<<<NV, 128, 0, stream>>>(adj, Th2, Ph2, gc_bt + 128,
        gc_wt + 2 * WSZ, gc_wp + 2 * WSZ, gc_bp + 256, nullptr, nullptr, Th, Ph);
    econv_fused_kernel<<<NV, 128, 0, stream>>>(adj, Th, Ph, gc_bt + 256,
        gc_wt + 3 * WSZ, gc_wp + 3 * WSZ, gc_bp + 384, nullptr, nullptr, Th2, Ph2);
    econv_fused_kernel<<<NV, 128, 0, stream>>>(adj, Th2, Ph2, gc_bt + 384,
        nullptr, nullptr, nullptr, er_w1, uu2, nullptr, nullptr);

    edge_kernel<<<NV, 256, 0, stream>>>(uu1, uu2, er_b1, er_w2, er_b2, out);
}

// Round 9
// 247.246 us; speedup vs baseline: 1.2825x; 1.0660x over previous
//
#include <hip/hip_runtime.h>
#include <math.h>

#define NDET 256
#define NTRK 256
#define NV   512
#define PPTS 512

typedef short bf16x8 __attribute__((ext_vector_type(8)));
typedef float f32x4  __attribute__((ext_vector_type(4)));

__device__ __forceinline__ float sigf(float x) { return 1.f / (1.f + expf(-x)); }

__device__ __forceinline__ short f2bf(float f) {
    unsigned u = __float_as_uint(f);
    u += 0x7fffu + ((u >> 16) & 1u);          // RNE
    return (short)(u >> 16);
}
__device__ __forceinline__ unsigned pack2bf(float lo, float hi) {
    return (unsigned)(unsigned short)f2bf(lo) | ((unsigned)(unsigned short)f2bf(hi) << 16);
}

// ---------------------------------------------------------------------------
// PointNet (bf16 MFMA stages 2/3) + fused det-motion MLP tail for det blocks.
// Separate from LSTM on purpose: merging them into one kernel makes the
// register allocator pick one budget (136) for both paths and spill the
// LSTM weights (round-6/7 regression, measured).
// ---------------------------------------------------------------------------
__global__ __launch_bounds__(256) void pointnet_kernel(
    const float* __restrict__ det_pts, const float* __restrict__ track_pts,
    const float* __restrict__ w1, const float* __restrict__ b1,
    const float* __restrict__ w2, const float* __restrict__ b2,
    const float* __restrict__ w3, const float* __restrict__ b3,
    const float* __restrict__ det_boxes,
    const float* __restrict__ dw1, const float* __restrict__ db1,
    const float* __restrict__ dw2, const float* __restrict__ db2,
    float* __restrict__ hout)
{
    __shared__ __align__(16) short sW2[128][72];
    __shared__ __align__(16) short sW3[64][136];
    __shared__ __align__(16) short sH1[64][72];
    __shared__ __align__(16) short sH2[64][136];
    __shared__ __align__(16) float sX[320];
    __shared__ float sW1f[64][6];
    __shared__ float sB1[64];
    __shared__ float sbox[9];
    __shared__ float sh32[32];

    const int t  = threadIdx.x;
    const int b  = blockIdx.x;
    const int w  = t >> 6;
    const int ln = t & 15;
    const int kq = (t >> 4) & 3;
    const float* x = (b < NDET) ? (det_pts + (size_t)b * PPTS * 5)
                                : (track_pts + (size_t)(b - NDET) * PPTS * 5);

    for (int i = t; i < 8192; i += 256) sW2[i >> 6][i & 63] = f2bf(w2[i]);
    for (int i = t; i < 8192; i += 256) sW3[i >> 7][i & 127] = f2bf(w3[i]);
    for (int i = t; i < 320; i += 256) sW1f[i / 5][i % 5] = w1[i];
    if (t < 64) sB1[t] = b1[t];
    __syncthreads();

    bf16x8 bf2[2][2];
#pragma unroll
    for (int nt = 0; nt < 2; ++nt)
#pragma unroll
        for (int Kt = 0; Kt < 2; ++Kt)
            bf2[nt][Kt] = *(const bf16x8*)&sW2[32 * w + 16 * nt + ln][kq * 8 + 32 * Kt];
    bf16x8 bf3[4];
#pragma unroll
    for (int Kt = 0; Kt < 4; ++Kt)
        bf3[Kt] = *(const bf16x8*)&sW3[16 * w + ln][kq * 8 + 32 * Kt];
    float bn[2];
#pragma unroll
    for (int nt = 0; nt < 2; ++nt) bn[nt] = b2[32 * w + 16 * nt + ln];

    float runmax[4] = {-1e30f, -1e30f, -1e30f, -1e30f};

    const int pt = t & 63;
    for (int c = 0; c < PPTS / 64; ++c) {
        for (int i = t; i < 320; i += 256) sX[i] = x[c * 320 + i];
        __syncthreads();
        {
            float xv[5];
#pragma unroll
            for (int k = 0; k < 5; ++k) xv[k] = sX[pt * 5 + k];
#pragma unroll
            for (int jj = 0; jj < 8; ++jj) {
                const int d0 = w * 16 + 2 * jj;
                float a0 = sB1[d0], a1 = sB1[d0 + 1];
#pragma unroll
                for (int k = 0; k < 5; ++k) {
                    a0 = fmaf(xv[k], sW1f[d0][k], a0);
                    a1 = fmaf(xv[k], sW1f[d0 + 1][k], a1);
                }
                *(unsigned*)&sH1[pt][d0] = pack2bf(fmaxf(a0, 0.f), fmaxf(a1, 0.f));
            }
        }
        __syncthreads();
        {
            bf16x8 af[4][2];
#pragma unroll
            for (int Mt = 0; Mt < 4; ++Mt)
#pragma unroll
                for (int Kt = 0; Kt < 2; ++Kt)
                    af[Mt][Kt] = *(const bf16x8*)&sH1[16 * Mt + ln][kq * 8 + 32 * Kt];
#pragma unroll
            for (int Mt = 0; Mt < 4; ++Mt) {
#pragma unroll
                for (int nt = 0; nt < 2; ++nt) {
                    f32x4 cacc = {0.f, 0.f, 0.f, 0.f};
                    cacc = __builtin_amdgcn_mfma_f32_16x16x32_bf16(af[Mt][0], bf2[nt][0], cacc, 0, 0, 0);
                    cacc = __builtin_amdgcn_mfma_f32_16x16x32_bf16(af[Mt][1], bf2[nt][1], cacc, 0, 0, 0);
                    const int col = 32 * w + 16 * nt + ln;
#pragma unroll
                    for (int r = 0; r < 4; ++r)
                        sH2[16 * Mt + kq * 4 + r][col] = f2bf(fmaxf(cacc[r] + bn[nt], 0.f));
                }
            }
        }
        __syncthreads();
        {
#pragma unroll
            for (int Mt = 0; Mt < 4; ++Mt) {
                f32x4 cacc = {0.f, 0.f, 0.f, 0.f};
#pragma unroll
                for (int Kt = 0; Kt < 4; ++Kt) {
                    const bf16x8 a = *(const bf16x8*)&sH2[16 * Mt + ln][kq * 8 + 32 * Kt];
                    cacc = __builtin_amdgcn_mfma_f32_16x16x32_bf16(a, bf3[Kt], cacc, 0, 0, 0);
                }
#pragma unroll
                for (int r = 0; r < 4; ++r) runmax[r] = fmaxf(runmax[r], cacc[r]);
            }
        }
        __syncthreads();
    }

    float rm = fmaxf(fmaxf(runmax[0], runmax[1]), fmaxf(runmax[2], runmax[3]));
    rm = fmaxf(rm, __shfl_xor(rm, 16));
    rm = fmaxf(rm, __shfl_xor(rm, 32));
    if ((t & 63) < 16) {
        const int n = 16 * w + ln;
        hout[b * 128 + n] = rm + b3[n];
    }

    if (b < NDET) {
        if (t < 9) sbox[t] = det_boxes[b * 9 + t];
        __syncthreads();
        if (t < 32) {
            float a = db1[t];
#pragma unroll
            for (int k = 0; k < 9; ++k) a = fmaf(dw1[t * 9 + k], sbox[k], a);
            sh32[t] = fmaxf(a, 0.f);
        }
        __syncthreads();
        if (t < 64) {
            float a = db2[t];
#pragma unroll
            for (int k = 0; k < 32; ++k) a = fmaf(dw2[t * 32 + k], sh32[k], a);
            hout[b * 128 + 64 + t] = a;
        }
    }
}

// ---------------------------------------------------------------------------
// Fused 2-layer LSTM, row-parallel (round-5 version, VGPR 256, no spill).
// ---------------------------------------------------------------------------
__global__ __launch_bounds__(256, 1) void lstm_kernel(
    const float* __restrict__ track_boxes,
    const float* __restrict__ wih0, const float* __restrict__ whh0,
    const float* __restrict__ bih0, const float* __restrict__ bhh0,
    const float* __restrict__ wih1, const float* __restrict__ whh1,
    const float* __restrict__ bih1, const float* __restrict__ bhh1,
    float* __restrict__ hout)
{
    __shared__ float sx[90];
    __shared__ float sg[256];
    __shared__ __align__(16) float sh0[64];
    __shared__ __align__(16) float sh1[64];

    const int t = threadIdx.x;
    const int m = blockIdx.x;
    const int u = t & 63;

    if (t < 90) sx[t] = track_boxes[m * 90 + t];
    if (t < 64) { sh0[t] = 0.f; sh1[t] = 0.f; }

    float w0[9];
#pragma unroll
    for (int k = 0; k < 9; ++k) w0[k] = wih0[t * 9 + k];
    float4 wr0[16], wi1[16], wr1[16];
    {
        const float4* p0 = (const float4*)(whh0 + t * 64);
        const float4* p1 = (const float4*)(wih1 + t * 64);
        const float4* p2 = (const float4*)(whh1 + t * 64);
#pragma unroll
        for (int k = 0; k < 16; ++k) { wr0[k] = p0[k]; wi1[k] = p1[k]; wr1[k] = p2[k]; }
    }
    const float bias0 = bih0[t] + bhh0[t];
    const float bias1 = bih1[t] + bhh1[t];

    float c0 = 0.f, c1 = 0.f, h1reg = 0.f;
    __syncthreads();

    for (int s = 0; s < 10; ++s) {
        {
            float acc0 = bias0, acc1 = 0.f, acc2 = 0.f, acc3 = 0.f;
#pragma unroll
            for (int k = 0; k < 9; ++k) acc0 = fmaf(w0[k], sx[s * 9 + k], acc0);
            const float4* hv = (const float4*)sh0;
#pragma unroll
            for (int k = 0; k < 16; k += 4) {
                float4 hA = hv[k], hB = hv[k + 1], hC = hv[k + 2], hD = hv[k + 3];
                acc0 = fmaf(wr0[k].x, hA.x, acc0); acc0 = fmaf(wr0[k].y, hA.y, acc0);
                acc0 = fmaf(wr0[k].z, hA.z, acc0); acc0 = fmaf(wr0[k].w, hA.w, acc0);
                acc1 = fmaf(wr0[k+1].x, hB.x, acc1); acc1 = fmaf(wr0[k+1].y, hB.y, acc1);
                acc1 = fmaf(wr0[k+1].z, hB.z, acc1); acc1 = fmaf(wr0[k+1].w, hB.w, acc1);
                acc2 = fmaf(wr0[k+2].x, hC.x, acc2); acc2 = fmaf(wr0[k+2].y, hC.y, acc2);
                acc2 = fmaf(wr0[k+2].z, hC.z, acc2); acc2 = fmaf(wr0[k+2].w, hC.w, acc2);
                acc3 = fmaf(wr0[k+3].x, hD.x, acc3); acc3 = fmaf(wr0[k+3].y, hD.y, acc3);
                acc3 = fmaf(wr0[k+3].z, hD.z, acc3); acc3 = fmaf(wr0[k+3].w, hD.w, acc3);
            }
            sg[t] = (acc0 + acc1) + (acc2 + acc3);
        }
        __syncthreads();
        if (t < 64) {
            const float gi = sg[u], gf = sg[64 + u], gg = sg[128 + u], go = sg[192 + u];
            c0 = sigf(gf) * c0 + sigf(gi) * tanhf(gg);
            sh0[u] = sigf(go) * tanhf(c0);
        }
        __syncthreads();
        {
            float acc0 = bias1, acc1 = 0.f, acc2 = 0.f, acc3 = 0.f;
            const float4* xv = (const float4*)sh0;
            const float4* hv = (const float4*)sh1;
#pragma unroll
            for (int k = 0; k < 16; k += 4) {
                float4 xA = xv[k], xB = xv[k + 1], xC = xv[k + 2], xD = xv[k + 3];
                acc0 = fmaf(wi1[k].x, xA.x, acc0); acc0 = fmaf(wi1[k].y, xA.y, acc0);
                acc0 = fmaf(wi1[k].z, xA.z, acc0); acc0 = fmaf(wi1[k].w, xA.w, acc0);
                acc1 = fmaf(wi1[k+1].x, xB.x, acc1); acc1 = fmaf(wi1[k+1].y, xB.y, acc1);
                acc1 = fmaf(wi1[k+1].z, xB.z, acc1); acc1 = fmaf(wi1[k+1].w, xB.w, acc1);
                acc2 = fmaf(wi1[k+2].x, xC.x, acc2); acc2 = fmaf(wi1[k+2].y, xC.y, acc2);
                acc2 = fmaf(wi1[k+2].z, xC.z, acc2); acc2 = fmaf(wi1[k+2].w, xC.w, acc2);
                acc3 = fmaf(wi1[k+3].x, xD.x, acc3); acc3 = fmaf(wi1[k+3].y, xD.y, acc3);
                acc3 = fmaf(wi1[k+3].z, xD.z, acc3); acc3 = fmaf(wi1[k+3].w, xD.w, acc3);
            }
#pragma unroll
            for (int k = 0; k < 16; k += 4) {
                float4 hA = hv[k], hB = hv[k + 1], hC = hv[k + 2], hD = hv[k + 3];
                acc0 = fmaf(wr1[k].x, hA.x, acc0); acc0 = fmaf(wr1[k].y, hA.y, acc0);
                acc0 = fmaf(wr1[k].z, hA.z, acc0); acc0 = fmaf(wr1[k].w, hA.w, acc0);
                acc1 = fmaf(wr1[k+1].x, hB.x, acc1); acc1 = fmaf(wr1[k+1].y, hB.y, acc1);
                acc1 = fmaf(wr1[k+1].z, hB.z, acc1); acc1 = fmaf(wr1[k+1].w, hB.w, acc1);
                acc2 = fmaf(wr1[k+2].x, hC.x, acc2); acc2 = fmaf(wr1[k+2].y, hC.y, acc2);
                acc2 = fmaf(wr1[k+2].z, hC.z, acc2); acc2 = fmaf(wr1[k+2].w, hC.w, acc2);
                acc3 = fmaf(wr1[k+3].x, hD.x, acc3); acc3 = fmaf(wr1[k+3].y, hD.y, acc3);
                acc3 = fmaf(wr1[k+3].z, hD.z, acc3); acc3 = fmaf(wr1[k+3].w, hD.w, acc3);
            }
            sg[t] = (acc0 + acc1) + (acc2 + acc3);
        }
        __syncthreads();
        if (t < 64) {
            const float gi = sg[u], gf = sg[64 + u], gg = sg[128 + u], go = sg[192 + u];
            c1 = sigf(gf) * c1 + sigf(gi) * tanhf(gg);
            h1reg = sigf(go) * tanhf(c1);
            sh1[u] = h1reg;
        }
        __syncthreads();
    }

    if (t < 64) hout[(size_t)(NDET + m) * 128 + 64 + u] = h1reg;
}

// ---------------------------------------------------------------------------
// EdgeConv layer-0 GEMMs: one block per vertex.
// ---------------------------------------------------------------------------
__global__ __launch_bounds__(128) void econv_gemm_kernel(
    const float* __restrict__ hin, const float* __restrict__ wt,
    const float* __restrict__ wp, const float* __restrict__ bp,
    float* __restrict__ Th, float* __restrict__ Ph)
{
    __shared__ __align__(16) float srow[128];
    const int t = threadIdx.x, v = blockIdx.x;
    srow[t] = hin[v * 128 + t];
    __syncthreads();
    const float4* hr = (const float4*)srow;
    const float4* wtr = (const float4*)(wt + t * 128);
    const float4* wpr = (const float4*)(wp + t * 128);
    float aT = 0.f, aP = bp[t];
#pragma unroll 8
    for (int k = 0; k < 32; ++k) {
        const float4 h = hr[k];
        const float4 a = wtr[k];
        aT = fmaf(a.x, h.x, aT); aT = fmaf(a.y, h.y, aT);
        aT = fmaf(a.z, h.z, aT); aT = fmaf(a.w, h.w, aT);
        const float4 b = wpr[k];
        aP = fmaf(b.x, h.x, aP); aP = fmaf(b.y, h.y, aP);
        aP = fmaf(b.z, h.z, aP); aP = fmaf(b.w, h.w, aP);
    }
    Th[v * 128 + t] = aT;
    Ph[v * 128 + t] = aP;
}

// ---------------------------------------------------------------------------
// Fused EdgeConv: masked neighbor-max + combine + relu (h_i stays in LDS),
// then optional next-layer GEMM and optional uproj.
// ---------------------------------------------------------------------------
__global__ __launch_bounds__(128) void econv_fused_kernel(
    const int* __restrict__ adj, const float* __restrict__ Th,
    const float* __restrict__ Ph, const float* __restrict__ bt,
    const float* __restrict__ wtn, const float* __restrict__ wpn,
    const float* __restrict__ bpn,
    const float* __restrict__ erw1, float* __restrict__ uu,
    float* __restrict__ Thn, float* __restrict__ Phn)
{
    __shared__ float sneg[NV];                       // 0 / -3e38 mask bias
    __shared__ __align__(16) float4 sred[4][32];     // per-group partial max
    __shared__ __align__(16) float sh[128];          // h_i row

    const int t = threadIdx.x, i = blockIdx.x;
    const int l32 = t & 31, grp = t >> 5;

    for (int j = t; j < NV; j += 128)
        sneg[j] = ((adj[j * NV + i] != 0) || (j == i)) ? 0.f : -3e38f;

    const float thi = Th[i * 128 + t];
    const float phi = Ph[i * 128 + t];
    const float btv = bt[t];
    __syncthreads();

    float4 mx = {-3e38f, -3e38f, -3e38f, -3e38f};
    const float* __restrict__ thp = Th + 4 * l32;
#pragma unroll 4
    for (int jb = 0; jb < NV; jb += 16) {
        float4 v[4];
#pragma unroll
        for (int jj = 0; jj < 4; ++jj)
            v[jj] = *(const float4*)&thp[(size_t)(jb + 4 * jj + grp) * 128];
#pragma unroll
        for (int jj = 0; jj < 4; ++jj) {
            const float s = sneg[jb + 4 * jj + grp];
            mx.x = fmaxf(mx.x, v[jj].x + s);
            mx.y = fmaxf(mx.y, v[jj].y + s);
            mx.z = fmaxf(mx.z, v[jj].z + s);
            mx.w = fmaxf(mx.w, v[jj].w + s);
        }
    }
    sred[grp][l32] = mx;
    __syncthreads();

    const float* rf = (const float*)sred;
    const float m = fmaxf(fmaxf(rf[t], rf[128 + t]), fmaxf(rf[256 + t], rf[384 + t]));
    sh[t] = fmaxf(m - thi + btv + phi, 0.f);
    __syncthreads();

    const float4* hr = (const float4*)sh;
    if (wtn) {
        const float4* wtr = (const float4*)(wtn + t * 128);
        const float4* wpr = (const float4*)(wpn + t * 128);
        float aT = 0.f, aP = bpn[t];
#pragma unroll 8
        for (int k = 0; k < 32; ++k) {
            const float4 h = hr[k];
            const float4 a = wtr[k];
            aT = fmaf(a.x, h.x, aT); aT = fmaf(a.y, h.y, aT);
            aT = fmaf(a.z, h.z, aT); aT = fmaf(a.w, h.w, aT);
            const float4 b = wpr[k];
            aP = fmaf(b.x, h.x, aP); aP = fmaf(b.y, h.y, aP);
            aP = fmaf(b.z, h.z, aP); aP = fmaf(b.w, h.w, aP);
        }
        Thn[i * 128 + t] = aT;
        Phn[i * 128 + t] = aP;
    }
    if (erw1 && i < NDET && t < 64) {
        const float4* wr = (const float4*)(erw1 + t * 128);
        float a = 0.f;
#pragma unroll 8
        for (int k = 0; k < 32; ++k) {
            const float4 h = hr[k], wv = wr[k];
            a = fmaf(wv.x, h.x, a); a = fmaf(wv.y, h.y, a);
            a = fmaf(wv.z, h.z, a); a = fmaf(wv.w, h.w, a);
        }
        uu[i * 64 + t] = a;
    }
}

// ---------------------------------------------------------------------------
// Both affinities in one launch (grid 512): blocks <256 -> aff1, else final.
// ---------------------------------------------------------------------------
__global__ __launch_bounds__(256) void edge_kernel(
    const float* __restrict__ uu1, const float* __restrict__ uu2,
    const float* __restrict__ b1, const float* __restrict__ w2,
    const float* __restrict__ b2, float* __restrict__ out)
{
    __shared__ float sui[64], sw2[64], sb1[64];
    const int t = threadIdx.x, blk = blockIdx.x;
    const float* u = (blk < NDET) ? uu1 : uu2;
    float* o = (blk < NDET) ? out : out + NDET * NTRK;
    const int i = blk & (NDET - 1);
    if (t < 64) { sui[t] = u[i * 64 + t]; sw2[t] = w2[t]; sb1[t] = b1[t]; }
    __syncthreads();
    const float4* ur = (const float4*)(u + t * 64);
    float a = b2[0];
#pragma unroll
    for (int k = 0; k < 16; ++k) {
        const float4 uv = ur[k];
        const int k4 = k * 4;
        a = fmaf(sw2[k4 + 0], fmaxf(uv.x - sui[k4 + 0] + sb1[k4 + 0], 0.f), a);
        a = fmaf(sw2[k4 + 1], fmaxf(uv.y - sui[k4 + 1] + sb1[k4 + 1], 0.f), a);
        a = fmaf(sw2[k4 + 2], fmaxf(uv.z - sui[k4 + 2] + sb1[k4 + 2], 0.f), a);
        a = fmaf(sw2[k4 + 3], fmaxf(uv.w - sui[k4 + 3] + sb1[k4 + 3], 0.f), a);
    }
    o[i * 256 + t] = 1.f / (1.f + expf(-a));
}

// ---------------------------------------------------------------------------
extern "C" void kernel_launch(void* const* d_in, const int* in_sizes, int n_in,
                              void* d_out, int out_size, void* d_ws, size_t ws_size,
                              hipStream_t stream)
{
    const float* det_pts     = (const float*)d_in[0];
    const float* det_boxes   = (const float*)d_in[1];
    const float* track_pts   = (const float*)d_in[2];
    const float* track_boxes = (const float*)d_in[3];
    const int*   adj         = (const int*)d_in[4];
    const float* pn_w1 = (const float*)d_in[5],  *pn_b1 = (const float*)d_in[6];
    const float* pn_w2 = (const float*)d_in[7],  *pn_b2 = (const float*)d_in[8];
    const float* pn_w3 = (const float*)d_in[9],  *pn_b3 = (const float*)d_in[10];
    const float* dm_w1 = (const float*)d_in[11], *dm_b1 = (const float*)d_in[12];
    const float* dm_w2 = (const float*)d_in[13], *dm_b2 = (const float*)d_in[14];
    const float* l0_wih = (const float*)d_in[15], *l0_whh = (const float*)d_in[16];
    const float* l0_bih = (const float*)d_in[17], *l0_bhh = (const float*)d_in[18];
    const float* l1_wih = (const float*)d_in[19], *l1_whh = (const float*)d_in[20];
    const float* l1_bih = (const float*)d_in[21], *l1_bhh = (const float*)d_in[22];
    const float* gc_wt = (const float*)d_in[23], *gc_bt = (const float*)d_in[24];
    const float* gc_wp = (const float*)d_in[25], *gc_bp = (const float*)d_in[26];
    const float* er_w1 = (const float*)d_in[27], *er_b1 = (const float*)d_in[28];
    const float* er_w2 = (const float*)d_in[29], *er_b2 = (const float*)d_in[30];
    float* out = (float*)d_out;

    float* hA  = (float*)d_ws;           // [512][128]
    float* Th  = hA  + NV * 128;         // [512][128]
    float* Ph  = Th  + NV * 128;         // [512][128]
    float* Th2 = Ph  + NV * 128;         // [512][128]
    float* Ph2 = Th2 + NV * 128;         // [512][128]
    float* uu1 = Ph2 + NV * 128;         // [256][64]
    float* uu2 = uu1 + NDET * 64;        // [256][64]

    pointnet_kernel<<<NV, 256, 0, stream>>>(det_pts, track_pts,
        pn_w1, pn_b1, pn_w2, pn_b2, pn_w3, pn_b3,
        det_boxes, dm_w1, dm_b1, dm_w2, dm_b2, hA);
    lstm_kernel<<<NTRK, 256, 0, stream>>>(track_boxes,
        l0_wih, l0_whh, l0_bih, l0_bhh, l1_wih, l1_whh, l1_bih, l1_bhh, hA);

    econv_gemm_kernel<<<NV, 128, 0, stream>>>(hA, gc_wt, gc_wp, gc_bp, Th, Ph);

    const size_t WSZ = 128 * 128;
    econv_fused_kernel<<<NV, 128, 0, stream>>>(adj, Th, Ph, gc_bt,
        gc_wt + WSZ, gc_wp + WSZ, gc_bp + 128, er_w1, uu1, Th2, Ph2);
    econv_fused_kernel<<<NV, 128, 0, stream>>>(adj, Th2, Ph2, gc_bt + 128,
        gc_wt + 2 * WSZ, gc_wp + 2 * WSZ, gc_bp + 256, nullptr, nullptr, Th, Ph);
    econv_fused_kernel<<<NV, 128, 0, stream>>>(adj, Th, Ph, gc_bt + 256,
        gc_wt + 3 * WSZ, gc_wp + 3 * WSZ, gc_bp + 384, nullptr, nullptr, Th2, Ph2);
    econv_fused_kernel<<<NV, 128, 0, stream>>>(adj, Th2, Ph2, gc_bt + 384,
        nullptr, nullptr, nullptr, er_w1, uu2, nullptr, nullptr);

    edge_kernel<<<NV, 256, 0, stream>>>(uu1, uu2, er_b1, er_w2, er_b2, out);
}

// Round 10
// 244.367 us; speedup vs baseline: 1.2976x; 1.0118x over previous
//
#include <hip/hip_runtime.h>
#include <math.h>

#define NDET 256
#define NTRK 256
#define NV   512
#define PPTS 512

typedef short bf16x8 __attribute__((ext_vector_type(8)));
typedef float f32x4  __attribute__((ext_vector_type(4)));

__device__ __forceinline__ float sigf(float x) { return 1.f / (1.f + __expf(-x)); }
__device__ __forceinline__ float ftanh(float x) {
    const float xc = fmaxf(fminf(x, 15.f), -15.f);   // avoid inf/inf
    const float e = __expf(2.f * xc);
    return (e - 1.f) / (e + 1.f);
}

__device__ __forceinline__ short f2bf(float f) {
    unsigned u = __float_as_uint(f);
    u += 0x7fffu + ((u >> 16) & 1u);          // RNE
    return (short)(u >> 16);
}
__device__ __forceinline__ unsigned pack2bf(float lo, float hi) {
    return (unsigned)(unsigned short)f2bf(lo) | ((unsigned)(unsigned short)f2bf(hi) << 16);
}
__device__ __forceinline__ bf16x8 load_frag_bf16(const float* __restrict__ src) {
    const float4 a = *(const float4*)src;
    const float4 b = *(const float4*)(src + 4);
    bf16x8 r;
    r[0] = f2bf(a.x); r[1] = f2bf(a.y); r[2] = f2bf(a.z); r[3] = f2bf(a.w);
    r[4] = f2bf(b.x); r[5] = f2bf(b.y); r[6] = f2bf(b.z); r[7] = f2bf(b.w);
    return r;
}

// ---------------------------------------------------------------------------
// PointNet (bf16 MFMA stages 2/3) + fused det-motion MLP tail for det blocks.
// W2/W3 fragments are loaded DIRECTLY from global into registers (once per
// block, L2-resident) — no LDS staging. LDS ~30KB -> 5 blocks/CU (was 2).
// Kept separate from LSTM: merging forces one VGPR budget and spills the
// LSTM weights (round-6/7 regression, measured).
// ---------------------------------------------------------------------------
__global__ __launch_bounds__(256) void pointnet_kernel(
    const float* __restrict__ det_pts, const float* __restrict__ track_pts,
    const float* __restrict__ w1, const float* __restrict__ b1,
    const float* __restrict__ w2, const float* __restrict__ b2,
    const float* __restrict__ w3, const float* __restrict__ b3,
    const float* __restrict__ det_boxes,
    const float* __restrict__ dw1, const float* __restrict__ db1,
    const float* __restrict__ dw2, const float* __restrict__ db2,
    float* __restrict__ hout)
{
    __shared__ __align__(16) short sH1[64][72];
    __shared__ __align__(16) short sH2[64][136];
    __shared__ __align__(16) float sX[320];
    __shared__ float sW1f[64][6];
    __shared__ float sB1[64];
    __shared__ float sbox[9];
    __shared__ float sh32[32];

    const int t  = threadIdx.x;
    const int b  = blockIdx.x;
    const int w  = t >> 6;
    const int ln = t & 15;
    const int kq = (t >> 4) & 3;
    const float* x = (b < NDET) ? (det_pts + (size_t)b * PPTS * 5)
                                : (track_pts + (size_t)(b - NDET) * PPTS * 5);

    for (int i = t; i < 320; i += 256) sW1f[i / 5][i % 5] = w1[i];
    if (t < 64) sB1[t] = b1[t];

    // ---- B-fragments straight from global (w2:[128][64], w3:[64][128])
    bf16x8 bf2[2][2];
#pragma unroll
    for (int nt = 0; nt < 2; ++nt)
#pragma unroll
        for (int Kt = 0; Kt < 2; ++Kt)
            bf2[nt][Kt] = load_frag_bf16(w2 + (size_t)(32 * w + 16 * nt + ln) * 64 + kq * 8 + 32 * Kt);
    bf16x8 bf3[4];
#pragma unroll
    for (int Kt = 0; Kt < 4; ++Kt)
        bf3[Kt] = load_frag_bf16(w3 + (size_t)(16 * w + ln) * 128 + kq * 8 + 32 * Kt);
    float bn[2];
#pragma unroll
    for (int nt = 0; nt < 2; ++nt) bn[nt] = b2[32 * w + 16 * nt + ln];
    __syncthreads();

    float runmax[4] = {-1e30f, -1e30f, -1e30f, -1e30f};

    const int pt = t & 63;
    for (int c = 0; c < PPTS / 64; ++c) {
        for (int i = t; i < 320; i += 256) sX[i] = x[c * 320 + i];
        __syncthreads();
        {
            float xv[5];
#pragma unroll
            for (int k = 0; k < 5; ++k) xv[k] = sX[pt * 5 + k];
#pragma unroll
            for (int jj = 0; jj < 8; ++jj) {
                const int d0 = w * 16 + 2 * jj;
                float a0 = sB1[d0], a1 = sB1[d0 + 1];
#pragma unroll
                for (int k = 0; k < 5; ++k) {
                    a0 = fmaf(xv[k], sW1f[d0][k], a0);
                    a1 = fmaf(xv[k], sW1f[d0 + 1][k], a1);
                }
                *(unsigned*)&sH1[pt][d0] = pack2bf(fmaxf(a0, 0.f), fmaxf(a1, 0.f));
            }
        }
        __syncthreads();
        {
            bf16x8 af[4][2];
#pragma unroll
            for (int Mt = 0; Mt < 4; ++Mt)
#pragma unroll
                for (int Kt = 0; Kt < 2; ++Kt)
                    af[Mt][Kt] = *(const bf16x8*)&sH1[16 * Mt + ln][kq * 8 + 32 * Kt];
#pragma unroll
            for (int Mt = 0; Mt < 4; ++Mt) {
#pragma unroll
                for (int nt = 0; nt < 2; ++nt) {
                    f32x4 cacc = {0.f, 0.f, 0.f, 0.f};
                    cacc = __builtin_amdgcn_mfma_f32_16x16x32_bf16(af[Mt][0], bf2[nt][0], cacc, 0, 0, 0);
                    cacc = __builtin_amdgcn_mfma_f32_16x16x32_bf16(af[Mt][1], bf2[nt][1], cacc, 0, 0, 0);
                    const int col = 32 * w + 16 * nt + ln;
#pragma unroll
                    for (int r = 0; r < 4; ++r)
                        sH2[16 * Mt + kq * 4 + r][col] = f2bf(fmaxf(cacc[r] + bn[nt], 0.f));
                }
            }
        }
        __syncthreads();
        {
#pragma unroll
            for (int Mt = 0; Mt < 4; ++Mt) {
                f32x4 cacc = {0.f, 0.f, 0.f, 0.f};
#pragma unroll
                for (int Kt = 0; Kt < 4; ++Kt) {
                    const bf16x8 a = *(const bf16x8*)&sH2[16 * Mt + ln][kq * 8 + 32 * Kt];
                    cacc = __builtin_amdgcn_mfma_f32_16x16x32_bf16(a, bf3[Kt], cacc, 0, 0, 0);
                }
#pragma unroll
                for (int r = 0; r < 4; ++r) runmax[r] = fmaxf(runmax[r], cacc[r]);
            }
        }
        __syncthreads();
    }

    float rm = fmaxf(fmaxf(runmax[0], runmax[1]), fmaxf(runmax[2], runmax[3]));
    rm = fmaxf(rm, __shfl_xor(rm, 16));
    rm = fmaxf(rm, __shfl_xor(rm, 32));
    if ((t & 63) < 16) {
        const int n = 16 * w + ln;
        hout[b * 128 + n] = rm + b3[n];
    }

    if (b < NDET) {
        if (t < 9) sbox[t] = det_boxes[b * 9 + t];
        __syncthreads();
        if (t < 32) {
            float a = db1[t];
#pragma unroll
            for (int k = 0; k < 9; ++k) a = fmaf(dw1[t * 9 + k], sbox[k], a);
            sh32[t] = fmaxf(a, 0.f);
        }
        __syncthreads();
        if (t < 64) {
            float a = db2[t];
#pragma unroll
            for (int k = 0; k < 32; ++k) a = fmaf(dw2[t * 32 + k], sh32[k], a);
            hout[b * 128 + 64 + t] = a;
        }
    }
}

// ---------------------------------------------------------------------------
// Fused 2-layer LSTM, row-parallel (VGPR 256, no spill). Fast transcendentals
// (__expf-based sigmoid/tanh; ~1e-6 rel err, invisible at output).
// ---------------------------------------------------------------------------
__global__ __launch_bounds__(256, 1) void lstm_kernel(
    const float* __restrict__ track_boxes,
    const float* __restrict__ wih0, const float* __restrict__ whh0,
    const float* __restrict__ bih0, const float* __restrict__ bhh0,
    const float* __restrict__ wih1, const float* __restrict__ whh1,
    const float* __restrict__ bih1, const float* __restrict__ bhh1,
    float* __restrict__ hout)
{
    __shared__ float sx[90];
    __shared__ float sg[256];
    __shared__ __align__(16) float sh0[64];
    __shared__ __align__(16) float sh1[64];

    const int t = threadIdx.x;
    const int m = blockIdx.x;
    const int u = t & 63;

    if (t < 90) sx[t] = track_boxes[m * 90 + t];
    if (t < 64) { sh0[t] = 0.f; sh1[t] = 0.f; }

    float w0[9];
#pragma unroll
    for (int k = 0; k < 9; ++k) w0[k] = wih0[t * 9 + k];
    float4 wr0[16], wi1[16], wr1[16];
    {
        const float4* p0 = (const float4*)(whh0 + t * 64);
        const float4* p1 = (const float4*)(wih1 + t * 64);
        const float4* p2 = (const float4*)(whh1 + t * 64);
#pragma unroll
        for (int k = 0; k < 16; ++k) { wr0[k] = p0[k]; wi1[k] = p1[k]; wr1[k] = p2[k]; }
    }
    const float bias0 = bih0[t] + bhh0[t];
    const float bias1 = bih1[t] + bhh1[t];

    float c0 = 0.f, c1 = 0.f, h1reg = 0.f;
    __syncthreads();

    for (int s = 0; s < 10; ++s) {
        {
            float acc0 = bias0, acc1 = 0.f, acc2 = 0.f, acc3 = 0.f;
#pragma unroll
            for (int k = 0; k < 9; ++k) acc0 = fmaf(w0[k], sx[s * 9 + k], acc0);
            const float4* hv = (const float4*)sh0;
#pragma unroll
            for (int k = 0; k < 16; k += 4) {
                float4 hA = hv[k], hB = hv[k + 1], hC = hv[k + 2], hD = hv[k + 3];
                acc0 = fmaf(wr0[k].x, hA.x, acc0); acc0 = fmaf(wr0[k].y, hA.y, acc0);
                acc0 = fmaf(wr0[k].z, hA.z, acc0); acc0 = fmaf(wr0[k].w, hA.w, acc0);
                acc1 = fmaf(wr0[k+1].x, hB.x, acc1); acc1 = fmaf(wr0[k+1].y, hB.y, acc1);
                acc1 = fmaf(wr0[k+1].z, hB.z, acc1); acc1 = fmaf(wr0[k+1].w, hB.w, acc1);
                acc2 = fmaf(wr0[k+2].x, hC.x, acc2); acc2 = fmaf(wr0[k+2].y, hC.y, acc2);
                acc2 = fmaf(wr0[k+2].z, hC.z, acc2); acc2 = fmaf(wr0[k+2].w, hC.w, acc2);
                acc3 = fmaf(wr0[k+3].x, hD.x, acc3); acc3 = fmaf(wr0[k+3].y, hD.y, acc3);
                acc3 = fmaf(wr0[k+3].z, hD.z, acc3); acc3 = fmaf(wr0[k+3].w, hD.w, acc3);
            }
            sg[t] = (acc0 + acc1) + (acc2 + acc3);
        }
        __syncthreads();
        if (t < 64) {
            const float gi = sg[u], gf = sg[64 + u], gg = sg[128 + u], go = sg[192 + u];
            c0 = sigf(gf) * c0 + sigf(gi) * ftanh(gg);
            sh0[u] = sigf(go) * ftanh(c0);
        }
        __syncthreads();
        {
            float acc0 = bias1, acc1 = 0.f, acc2 = 0.f, acc3 = 0.f;
            const float4* xv = (const float4*)sh0;
            const float4* hv = (const float4*)sh1;
#pragma unroll
            for (int k = 0; k < 16; k += 4) {
                float4 xA = xv[k], xB = xv[k + 1], xC = xv[k + 2], xD = xv[k + 3];
                acc0 = fmaf(wi1[k].x, xA.x, acc0); acc0 = fmaf(wi1[k].y, xA.y, acc0);
                acc0 = fmaf(wi1[k].z, xA.z, acc0); acc0 = fmaf(wi1[k].w, xA.w, acc0);
                acc1 = fmaf(wi1[k+1].x, xB.x, acc1); acc1 = fmaf(wi1[k+1].y, xB.y, acc1);
                acc1 = fmaf(wi1[k+1].z, xB.z, acc1); acc1 = fmaf(wi1[k+1].w, xB.w, acc1);
                acc2 = fmaf(wi1[k+2].x, xC.x, acc2); acc2 = fmaf(wi1[k+2].y, xC.y, acc2);
                acc2 = fmaf(wi1[k+2].z, xC.z, acc2); acc2 = fmaf(wi1[k+2].w, xC.w, acc2);
                acc3 = fmaf(wi1[k+3].x, xD.x, acc3); acc3 = fmaf(wi1[k+3].y, xD.y, acc3);
                acc3 = fmaf(wi1[k+3].z, xD.z, acc3); acc3 = fmaf(wi1[k+3].w, xD.w, acc3);
            }
#pragma unroll
            for (int k = 0; k < 16; k += 4) {
                float4 hA = hv[k], hB = hv[k + 1], hC = hv[k + 2], hD = hv[k + 3];
                acc0 = fmaf(wr1[k].x, hA.x, acc0); acc0 = fmaf(wr1[k].y, hA.y, acc0);
                acc0 = fmaf(wr1[k].z, hA.z, acc0); acc0 = fmaf(wr1[k].w, hA.w, acc0);
                acc1 = fmaf(wr1[k+1].x, hB.x, acc1); acc1 = fmaf(wr1[k+1].y, hB.y, acc1);
                acc1 = fmaf(wr1[k+1].z, hB.z, acc1); acc1 = fmaf(wr1[k+1].w, hB.w, acc1);
                acc2 = fmaf(wr1[k+2].x, hC.x, acc2); acc2 = fmaf(wr1[k+2].y, hC.y, acc2);
                acc2 = fmaf(wr1[k+2].z, hC.z, acc2); acc2 = fmaf(wr1[k+2].w, hC.w, acc2);
                acc3 = fmaf(wr1[k+3].x, hD.x, acc3); acc3 = fmaf(wr1[k+3].y, hD.y, acc3);
                acc3 = fmaf(wr1[k+3].z, hD.z, acc3); acc3 = fmaf(wr1[k+3].w, hD.w, acc3);
            }
            sg[t] = (acc0 + acc1) + (acc2 + acc3);
        }
        __syncthreads();
        if (t < 64) {
            const float gi = sg[u], gf = sg[64 + u], gg = sg[128 + u], go = sg[192 + u];
            c1 = sigf(gf) * c1 + sigf(gi) * ftanh(gg);
            h1reg = sigf(go) * ftanh(c1);
            sh1[u] = h1reg;
        }
        __syncthreads();
    }

    if (t < 64) hout[(size_t)(NDET + m) * 128 + 64 + u] = h1reg;
}

// ---------------------------------------------------------------------------
// EdgeConv layer-0 GEMMs: one block per vertex.
// ---------------------------------------------------------------------------
__global__ __launch_bounds__(128) void econv_gemm_kernel(
    const float* __restrict__ hin, const float* __restrict__ wt,
    const float* __restrict__ wp, const float* __restrict__ bp,
    float* __restrict__ Th, float* __restrict__ Ph)
{
    __shared__ __align__(16) float srow[128];
    const int t = threadIdx.x, v = blockIdx.x;
    srow[t] = hin[v * 128 + t];
    __syncthreads();
    const float4* hr = (const float4*)srow;
    const float4* wtr = (const float4*)(wt + t * 128);
    const float4* wpr = (const float4*)(wp + t * 128);
    float aT = 0.f, aP = bp[t];
#pragma unroll 8
    for (int k = 0; k < 32; ++k) {
        const float4 h = hr[k];
        const float4 a = wtr[k];
        aT = fmaf(a.x, h.x, aT); aT = fmaf(a.y, h.y, aT);
        aT = fmaf(a.z, h.z, aT); aT = fmaf(a.w, h.w, aT);
        const float4 b = wpr[k];
        aP = fmaf(b.x, h.x, aP); aP = fmaf(b.y, h.y, aP);
        aP = fmaf(b.z, h.z, aP); aP = fmaf(b.w, h.w, aP);
    }
    Th[v * 128 + t] = aT;
    Ph[v * 128 + t] = aP;
}

// ---------------------------------------------------------------------------
// Fused EdgeConv: masked neighbor-max + combine + relu (h_i stays in LDS),
// then optional next-layer GEMM and optional uproj.
// ---------------------------------------------------------------------------
__global__ __launch_bounds__(128) void econv_fused_kernel(
    const int* __restrict__ adj, const float* __restrict__ Th,
    const float* __restrict__ Ph, const float* __restrict__ bt,
    const float* __restrict__ wtn, const float* __restrict__ wpn,
    const float* __restrict__ bpn,
    const float* __restrict__ erw1, float* __restrict__ uu,
    float* __restrict__ Thn, float* __restrict__ Phn)
{
    __shared__ float sneg[NV];                       // 0 / -3e38 mask bias
    __shared__ __align__(16) float4 sred[4][32];     // per-group partial max
    __shared__ __align__(16) float sh[128];          // h_i row

    const int t = threadIdx.x, i = blockIdx.x;
    const int l32 = t & 31, grp = t >> 5;

    for (int j = t; j < NV; j += 128)
        sneg[j] = ((adj[j * NV + i] != 0) || (j == i)) ? 0.f : -3e38f;

    const float thi = Th[i * 128 + t];
    const float phi = Ph[i * 128 + t];
    const float btv = bt[t];
    __syncthreads();

    float4 mx = {-3e38f, -3e38f, -3e38f, -3e38f};
    const float* __restrict__ thp = Th + 4 * l32;
#pragma unroll 4
    for (int jb = 0; jb < NV; jb += 16) {
        float4 v[4];
#pragma unroll
        for (int jj = 0; jj < 4; ++jj)
            v[jj] = *(const float4*)&thp[(size_t)(jb + 4 * jj + grp) * 128];
#pragma unroll
        for (int jj = 0; jj < 4; ++jj) {
            const float s = sneg[jb + 4 * jj + grp];
            mx.x = fmaxf(mx.x, v[jj].x + s);
            mx.y = fmaxf(mx.y, v[jj].y + s);
            mx.z = fmaxf(mx.z, v[jj].z + s);
            mx.w = fmaxf(mx.w, v[jj].w + s);
        }
    }
    sred[grp][l32] = mx;
    __syncthreads();

    const float* rf = (const float*)sred;
    const float m = fmaxf(fmaxf(rf[t], rf[128 + t]), fmaxf(rf[256 + t], rf[384 + t]));
    sh[t] = fmaxf(m - thi + btv + phi, 0.f);
    __syncthreads();

    const float4* hr = (const float4*)sh;
    if (wtn) {
        const float4* wtr = (const float4*)(wtn + t * 128);
        const float4* wpr = (const float4*)(wpn + t * 128);
        float aT = 0.f, aP = bpn[t];
#pragma unroll 8
        for (int k = 0; k < 32; ++k) {
            const float4 h = hr[k];
            const float4 a = wtr[k];
            aT = fmaf(a.x, h.x, aT); aT = fmaf(a.y, h.y, aT);
            aT = fmaf(a.z, h.z, aT); aT = fmaf(a.w, h.w, aT);
            const float4 b = wpr[k];
            aP = fmaf(b.x, h.x, aP); aP = fmaf(b.y, h.y, aP);
            aP = fmaf(b.z, h.z, aP); aP = fmaf(b.w, h.w, aP);
        }
        Thn[i * 128 + t] = aT;
        Phn[i * 128 + t] = aP;
    }
    if (erw1 && i < NDET && t < 64) {
        const float4* wr = (const float4*)(erw1 + t * 128);
        float a = 0.f;
#pragma unroll 8
        for (int k = 0; k < 32; ++k) {
            const float4 h = hr[k], wv = wr[k];
            a = fmaf(wv.x, h.x, a); a = fmaf(wv.y, h.y, a);
            a = fmaf(wv.z, h.z, a); a = fmaf(wv.w, h.w, a);
        }
        uu[i * 64 + t] = a;
    }
}

// ---------------------------------------------------------------------------
// Both affinities in one launch (grid 512): blocks <256 -> aff1, else final.
// ---------------------------------------------------------------------------
__global__ __launch_bounds__(256) void edge_kernel(
    const float* __restrict__ uu1, const float* __restrict__ uu2,
    const float* __restrict__ b1, const float* __restrict__ w2,
    const float* __restrict__ b2, float* __restrict__ out)
{
    __shared__ float sui[64], sw2[64], sb1[64];
    const int t = threadIdx.x, blk = blockIdx.x;
    const float* u = (blk < NDET) ? uu1 : uu2;
    float* o = (blk < NDET) ? out : out + NDET * NTRK;
    const int i = blk & (NDET - 1);
    if (t < 64) { sui[t] = u[i * 64 + t]; sw2[t] = w2[t]; sb1[t] = b1[t]; }
    __syncthreads();
    const float4* ur = (const float4*)(u + t * 64);
    float a = b2[0];
#pragma unroll
    for (int k = 0; k < 16; ++k) {
        const float4 uv = ur[k];
        const int k4 = k * 4;
        a = fmaf(sw2[k4 + 0], fmaxf(uv.x - sui[k4 + 0] + sb1[k4 + 0], 0.f), a);
        a = fmaf(sw2[k4 + 1], fmaxf(uv.y - sui[k4 + 1] + sb1[k4 + 1], 0.f), a);
        a = fmaf(sw2[k4 + 2], fmaxf(uv.z - sui[k4 + 2] + sb1[k4 + 2], 0.f), a);
        a = fmaf(sw2[k4 + 3], fmaxf(uv.w - sui[k4 + 3] + sb1[k4 + 3], 0.f), a);
    }
    o[i * 256 + t] = 1.f / (1.f + __expf(-a));
}

// ---------------------------------------------------------------------------
extern "C" void kernel_launch(void* const* d_in, const int* in_sizes, int n_in,
                              void* d_out, int out_size, void* d_ws, size_t ws_size,
                              hipStream_t stream)
{
    const float* det_pts     = (const float*)d_in[0];
    const float* det_boxes   = (const float*)d_in[1];
    const float* track_pts   = (const float*)d_in[2];
    const float* track_boxes = (const float*)d_in[3];
    const int*   adj         = (const int*)d_in[4];
    const float* pn_w1 = (const float*)d_in[5],  *pn_b1 = (const float*)d_in[6];
    const float* pn_w2 = (const float*)d_in[7],  *pn_b2 = (const float*)d_in[8];
    const float* pn_w3 = (const float*)d_in[9],  *pn_b3 = (const float*)d_in[10];
    const float* dm_w1 = (const float*)d_in[11], *dm_b1 = (const float*)d_in[12];
    const float* dm_w2 = (const float*)d_in[13], *dm_b2 = (const float*)d_in[14];
    const float* l0_wih = (const float*)d_in[15], *l0_whh = (const float*)d_in[16];
    const float* l0_bih = (const float*)d_in[17], *l0_bhh = (const float*)d_in[18];
    const float* l1_wih = (const float*)d_in[19], *l1_whh = (const float*)d_in[20];
    const float* l1_bih = (const float*)d_in[21], *l1_bhh = (const float*)d_in[22];
    const float* gc_wt = (const float*)d_in[23], *gc_bt = (const float*)d_in[24];
    const float* gc_wp = (const float*)d_in[25], *gc_bp = (const float*)d_in[26];
    const float* er_w1 = (const float*)d_in[27], *er_b1 = (const float*)d_in[28];
    const float* er_w2 = (const float*)d_in[29], *er_b2 = (const float*)d_in[30];
    float* out = (float*)d_out;

    float* hA  = (float*)d_ws;           // [512][128]
    float* Th  = hA  + NV * 128;         // [512][128]
    float* Ph  = Th  + NV * 128;         // [512][128]
    float* Th2 = Ph  + NV * 128;         // [512][128]
    float* Ph2 = Th2 + NV * 128;         // [512][128]
    float* uu1 = Ph2 + NV * 128;         // [256][64]
    float* uu2 = uu1 + NDET * 64;        // [256][64]

    pointnet_kernel<<<NV, 256, 0, stream>>>(det_pts, track_pts,
        pn_w1, pn_b1, pn_w2, pn_b2, pn_w3, pn_b3,
        det_boxes, dm_w1, dm_b1, dm_w2, dm_b2, hA);
    lstm_kernel<<<NTRK, 256, 0, stream>>>(track_boxes,
        l0_wih, l0_whh, l0_bih, l0_bhh, l1_wih, l1_whh, l1_bih, l1_bhh, hA);

    econv_gemm_kernel<<<NV, 128, 0, stream>>>(hA, gc_wt, gc_wp, gc_bp, Th, Ph);

    const size_t WSZ = 128 * 128;
    econv_fused_kernel<<<NV, 128, 0, stream>>>(adj, Th, Ph, gc_bt,
        gc_wt + WSZ, gc_wp + WSZ, gc_bp + 128, er_w1, uu1, Th2, Ph2);
    econv_fused_kernel<<<NV, 128, 0, stream>>>(adj, Th2, Ph2, gc_bt + 128,
        gc_wt + 2 * WSZ, gc_wp + 2 * WSZ, gc_bp + 256, nullptr, nullptr, Th, Ph);
    econv_fused_kernel<<<NV, 128, 0, stream>>>(adj, Th, Ph, gc_bt + 256,
        gc_wt + 3 * WSZ, gc_wp + 3 * WSZ, gc_bp + 384, nullptr, nullptr, Th2, Ph2);
    econv_fused_kernel<<<NV, 128, 0, stream>>>(adj, Th2, Ph2, gc_bt + 384,
        nullptr, nullptr, nullptr, er_w1, uu2, nullptr, nullptr);

    edge_kernel<<<NV, 256, 0, stream>>>(uu1, uu2, er_b1, er_w2, er_b2, out);
}